// Round 6
// baseline (690.927 us; speedup 1.0000x reference)
//
#include <hip/hip_runtime.h>
#include <hip/hip_bf16.h>

// ---------------------------------------------------------------------------
// Mlp_FMoE: fc1(MoE 2-expert top-1) -> DWConv3x3 -> GELU(exact) -> fc2(MoE)
// B=16 N=1024 C=512 Dh=2048 H=W=32, fp32 in/out.
// R6: conv rewritten as DMA-pipelined strip kernel (global_load_lds, counted
//     vmcnt, double-buffered 10-row tiles, zero-page halo); prep kernels
//     merged; GEMM occupancy bumps via launch_bounds.
// ---------------------------------------------------------------------------

#define TOKS  16384
#define CIN   512
#define DHID  2048

typedef __attribute__((ext_vector_type(8))) __bf16 bf16x8;
typedef __attribute__((ext_vector_type(4))) float  f32x4;
typedef __attribute__((ext_vector_type(4))) float  float4v;
typedef __attribute__((ext_vector_type(4))) unsigned short ushort4v;
typedef __attribute__((ext_vector_type(8))) unsigned short ushort8;

__device__ __forceinline__ unsigned short f2bf(float f) {
  union { float f; unsigned int u; } a; a.f = f;
  unsigned int u = a.u;
  unsigned int r = u + 0x7FFFu + ((u >> 16) & 1u);   // RNE
  return (unsigned short)(r >> 16);
}
__device__ __forceinline__ float bf2f(unsigned short h) {
  union { unsigned int u; float f; } a; a.u = ((unsigned int)h) << 16;
  return a.f;
}

// shift_quant: sign(w)*2^clip(round(log2(|w|+1e-12)),-14,0).
// round(log2(aw)) == e + (mantissa > sqrt(2)); exact via mantissa bit test.
__device__ __forceinline__ float squant(float w) {
  if (w == 0.0f) return 0.0f;
  float aw = fabsf(w) + 1e-12f;                 // fp32 add, as reference
  union { float f; unsigned u; } a; a.f = aw;
  int e = (int)((a.u >> 23) & 0xFFu) - 127;
  unsigned frac = a.u & 0x7FFFFFu;
  int shift = e + (frac >= 0x3504F4u ? 1 : 0);  // frac of sqrt(2)
  shift = min(max(shift, -14), 0);
  union { unsigned u; float f; } q; q.u = (unsigned)(shift + 127) << 23;
  return (w > 0.0f) ? q.f : -q.f;
}

#define GLDS16(gp, lp) __builtin_amdgcn_global_load_lds(                      \
    (const __attribute__((address_space(1))) void*)(gp),                      \
    (__attribute__((address_space(3))) void*)(lp), 16, 0, 0)

#define SBAR()  { __builtin_amdgcn_s_barrier(); __builtin_amdgcn_sched_barrier(0); }
#define VMCNT(n) asm volatile("s_waitcnt vmcnt(" #n ")" ::: "memory")

// ------------- merged prep: weights (blocks<4096) + x split/gate1 -----------
__global__ void k_prep(const float* __restrict__ w0, const float* __restrict__ w1,
                       const float* __restrict__ w20, const float* __restrict__ w21,
                       unsigned short* __restrict__ w0hi, unsigned short* __restrict__ w0lo,
                       unsigned short* __restrict__ w1q, unsigned short* __restrict__ w20b,
                       unsigned short* __restrict__ w21b,
                       const float* __restrict__ x, const float* __restrict__ wg1,
                       unsigned short* __restrict__ xhi, unsigned short* __restrict__ xlo,
                       unsigned char* __restrict__ pick1) {
  __shared__ float wg[1024];
  const int t = threadIdx.x;
  if (blockIdx.x < 4096) {
    int i = blockIdx.x * 256 + t;
    float v = w0[i];
    unsigned short h = f2bf(v);
    w0hi[i] = h;
    w0lo[i] = f2bf(v - bf2f(h));
    w1q[i]  = f2bf(squant(w1[i]));
    w20b[i] = f2bf(w20[i]);
    w21b[i] = f2bf(squant(w21[i]));
    return;
  }
  const int bid = blockIdx.x - 4096;
  #pragma unroll
  for (int i = 0; i < 4; ++i) wg[t + i * 256] = wg1[t + i * 256];
  __syncthreads();
  const int tok = bid * 4 + (t >> 6);
  const int l = t & 63;
  const float* xr = x + (size_t)tok * CIN + l * 8;
  float4v v0 = *(const float4v*)xr;
  float4v v1 = *(const float4v*)(xr + 4);
  float s0 = 0.f, s1 = 0.f;
  ushort8 hv, lv;
  #pragma unroll
  for (int j = 0; j < 8; ++j) {
    float v = (j < 4) ? v0[j] : v1[j - 4];
    unsigned short h = f2bf(v);
    hv[j] = h;
    lv[j] = f2bf(v - bf2f(h));
    int c = l * 8 + j;
    s0 += v * wg[c * 2];
    s1 += v * wg[c * 2 + 1];
  }
  *(ushort8*)&xhi[(size_t)tok * CIN + l * 8] = hv;
  *(ushort8*)&xlo[(size_t)tok * CIN + l * 8] = lv;
  for (int m = 32; m; m >>= 1) { s0 += __shfl_xor(s0, m); s1 += __shfl_xor(s1, m); }
  if (l == 0) pick1[tok] = (s0 >= s1) ? 0 : 1;   // argmax==0 on tie
}

// --------------- stable partition: perm = [expert0 toks..., expert1 toks...]
__global__ void k_scan(const unsigned char* __restrict__ pick, int* __restrict__ perm,
                       int* __restrict__ n0buf) {
  __shared__ int wpre[17];
  const int t = threadIdx.x;            // 1024
  const int lane = t & 63, w = t >> 6;  // 16 waves
  unsigned char loc[16]; int c0 = 0;
  #pragma unroll
  for (int i = 0; i < 16; ++i) { loc[i] = pick[t * 16 + i]; c0 += (loc[i] == 0); }
  int s = c0;
  #pragma unroll
  for (int off = 1; off < 64; off <<= 1) {
    int v = __shfl_up(s, off);
    if (lane >= off) s += v;
  }
  if (lane == 63) wpre[w + 1] = s;
  if (t == 0) wpre[0] = 0;
  __syncthreads();
  if (t == 0) {
    for (int j = 1; j <= 16; ++j) wpre[j] += wpre[j - 1];
    n0buf[0] = wpre[16];
  }
  __syncthreads();
  int total0 = wpre[16];
  int pre0 = wpre[w] + s - c0;
  int pre1 = t * 16 - pre0;
  int p0 = pre0, p1 = total0 + pre1;
  #pragma unroll
  for (int i = 0; i < 16; ++i) {
    int tok = t * 16 + i;
    if (loc[i] == 0) perm[p0++] = tok; else perm[p1++] = tok;
  }
}

// ------------------------- fc1 E0 (dense expert, bf16x3) --------------------
__launch_bounds__(256, 3)
__global__ void k_fc1_e0(const unsigned short* __restrict__ xhi,
                         const unsigned short* __restrict__ xlo,
                         const unsigned short* __restrict__ w0hi,
                         const unsigned short* __restrict__ w0lo,
                         const float* __restrict__ b0,
                         const int* __restrict__ perm, const int* __restrict__ n0buf,
                         float* __restrict__ h32) {
  __shared__ unsigned short sm[24576];   // 48 KiB: 3 bufs x {w0hi,w0lo} x 4096
  const int n0 = n0buf[0];
  const int t = threadIdx.x, wv = t >> 6, ln = t & 63;
  const int lr = ln & 15, lg = ln >> 4;
  const int g = blockIdx.x, q = g >> 3;
  const int tok0 = ((g & 7) + ((q >> 4) << 3)) * 128;
  const int nbase = (q & 15) * 128;
  if (tok0 >= n0) return;
  const int wm = (wv >> 1) * 64, wn = (wv & 1) * 64;

  int rowoff[4];
  #pragma unroll
  for (int mt = 0; mt < 4; ++mt)
    rowoff[mt] = perm[tok0 + wm + (mt << 4) + lr] * CIN + (lg << 3);

  const int swsrc = (((ln & 3) ^ ((ln >> 3) & 3)) << 3);
  const int swrd  = ((lg ^ ((lr >> 1) & 3)) << 3);

  f32x4 acc[4][4];
  #pragma unroll
  for (int i = 0; i < 4; ++i)
    #pragma unroll
    for (int j = 0; j < 4; ++j) acc[i][j] = f32x4{0.f, 0.f, 0.f, 0.f};

  auto STAGEB = [&](int kt, int db) {   // 4 GLDS per wave
    const int k0 = kt * 32;
    #pragma unroll
    for (int s = 0; s < 2; ++s) {
      const int rowblk = s * 4 + wv;
      size_t gb = (size_t)(nbase + (rowblk << 4) + (ln >> 2)) * CIN + k0 + swsrc;
      GLDS16(w0hi + gb, &sm[db * 8192 + (rowblk << 9)]);
      GLDS16(w0lo + gb, &sm[db * 8192 + 4096 + (rowblk << 9)]);
    }
  };
  auto LOADA = [&](bf16x8 (&ah)[4], bf16x8 (&al)[4], int kt) {
    const int k0 = kt * 32;
    #pragma unroll
    for (int mt = 0; mt < 4; ++mt) {
      ah[mt] = *(const bf16x8*)&xhi[rowoff[mt] + k0];
      al[mt] = *(const bf16x8*)&xlo[rowoff[mt] + k0];
    }
  };
  auto COMPUTE = [&](const bf16x8 (&ah)[4], const bf16x8 (&al)[4], int db) {
    __builtin_amdgcn_s_setprio(1);
    #pragma unroll
    for (int nt = 0; nt < 4; ++nt) {
      int bb = db * 8192 + (wn + (nt << 4) + lr) * 32 + swrd;
      bf16x8 bh = *(const bf16x8*)&sm[bb];
      bf16x8 bl = *(const bf16x8*)&sm[bb + 4096];
      #pragma unroll
      for (int mt = 0; mt < 4; ++mt) {
        acc[mt][nt] = __builtin_amdgcn_mfma_f32_16x16x32_bf16(ah[mt], bh, acc[mt][nt], 0, 0, 0);
        acc[mt][nt] = __builtin_amdgcn_mfma_f32_16x16x32_bf16(al[mt], bh, acc[mt][nt], 0, 0, 0);
        acc[mt][nt] = __builtin_amdgcn_mfma_f32_16x16x32_bf16(ah[mt], bl, acc[mt][nt], 0, 0, 0);
      }
    }
    __builtin_amdgcn_s_setprio(0);
  };

  bf16x8 Ah0[4], Al0[4], Ah1[4], Al1[4];
  LOADA(Ah0, Al0, 0);
  STAGEB(0, 0);
  STAGEB(1, 1);
  for (int kt = 0; kt < 14; kt += 2) {
    SBAR();
    LOADA(Ah1, Al1, kt + 1);
    STAGEB(kt + 2, (kt + 2) % 3);
    VMCNT(16);
    SBAR();
    COMPUTE(Ah0, Al0, kt % 3);
    SBAR();
    LOADA(Ah0, Al0, kt + 2);
    STAGEB(kt + 3, (kt + 3) % 3);
    VMCNT(16);
    SBAR();
    COMPUTE(Ah1, Al1, (kt + 1) % 3);
  }
  SBAR();
  LOADA(Ah1, Al1, 15);
  VMCNT(12);
  SBAR();
  COMPUTE(Ah0, Al0, 2);
  SBAR();
  VMCNT(0);
  SBAR();
  COMPUTE(Ah1, Al1, 0);

  __syncthreads();
  float* smf = (float*)sm;
  float bi[4];
  #pragma unroll
  for (int nt = 0; nt < 4; ++nt) bi[nt] = b0[nbase + wn + (nt << 4) + lr];
  #pragma unroll
  for (int mt = 0; mt < 4; ++mt) {
    #pragma unroll
    for (int nt = 0; nt < 4; ++nt) {
      f32x4 v = acc[mt][nt];
      #pragma unroll
      for (int rr = 0; rr < 4; ++rr)
        smf[wv * 1088 + ((lg << 2) + rr) * 68 + (nt << 4) + lr] = v[rr] + bi[nt];
    }
    #pragma unroll
    for (int p = 0; p < 4; ++p) {
      int row = (p << 2) + (ln >> 4);
      int pos = tok0 + wm + (mt << 4) + row;
      if (pos < n0) {
        f32x4 vv = *(const f32x4*)&smf[wv * 1088 + row * 68 + ((ln & 15) << 2)];
        *(f32x4*)&h32[(size_t)perm[pos] * DHID + nbase + wn + ((ln & 15) << 2)] = vv;
      }
    }
  }
}

// ------------------------- fc1 E1 (shift expert, bf16x2) --------------------
__launch_bounds__(256, 4)
__global__ void k_fc1_e1(const unsigned short* __restrict__ xhi,
                         const unsigned short* __restrict__ xlo,
                         const unsigned short* __restrict__ w1q,
                         const float* __restrict__ b1,
                         const int* __restrict__ perm, const int* __restrict__ n0buf,
                         float* __restrict__ h32) {
  __shared__ unsigned short sm[12288];   // 24 KiB
  const int n0 = n0buf[0];
  const int t = threadIdx.x, wv = t >> 6, ln = t & 63;
  const int lr = ln & 15, lg = ln >> 4;
  const int g = blockIdx.x, q = g >> 3;
  const int tok0 = ((g & 7) + ((q >> 4) << 3)) * 128;
  const int nbase = (q & 15) * 128;
  if (tok0 + 128 <= n0) return;
  const int wm = (wv >> 1) * 64, wn = (wv & 1) * 64;

  int rowoff[4];
  #pragma unroll
  for (int mt = 0; mt < 4; ++mt)
    rowoff[mt] = perm[tok0 + wm + (mt << 4) + lr] * CIN + (lg << 3);

  const int swsrc = (((ln & 3) ^ ((ln >> 3) & 3)) << 3);
  const int swrd  = ((lg ^ ((lr >> 1) & 3)) << 3);

  f32x4 acc[4][4];
  #pragma unroll
  for (int i = 0; i < 4; ++i)
    #pragma unroll
    for (int j = 0; j < 4; ++j) acc[i][j] = f32x4{0.f, 0.f, 0.f, 0.f};

  auto STAGEB = [&](int kt, int db) {   // 2 GLDS per wave
    const int k0 = kt * 32;
    #pragma unroll
    for (int s = 0; s < 2; ++s) {
      const int rowblk = s * 4 + wv;
      size_t gb = (size_t)(nbase + (rowblk << 4) + (ln >> 2)) * CIN + k0 + swsrc;
      GLDS16(w1q + gb, &sm[db * 4096 + (rowblk << 9)]);
    }
  };
  auto LOADA = [&](bf16x8 (&ah)[4], bf16x8 (&al)[4], int kt) {
    const int k0 = kt * 32;
    #pragma unroll
    for (int mt = 0; mt < 4; ++mt) {
      ah[mt] = *(const bf16x8*)&xhi[rowoff[mt] + k0];
      al[mt] = *(const bf16x8*)&xlo[rowoff[mt] + k0];
    }
  };
  auto COMPUTE = [&](const bf16x8 (&ah)[4], const bf16x8 (&al)[4], int db) {
    __builtin_amdgcn_s_setprio(1);
    #pragma unroll
    for (int nt = 0; nt < 4; ++nt) {
      bf16x8 bq = *(const bf16x8*)&sm[db * 4096 + (wn + (nt << 4) + lr) * 32 + swrd];
      #pragma unroll
      for (int mt = 0; mt < 4; ++mt) {
        acc[mt][nt] = __builtin_amdgcn_mfma_f32_16x16x32_bf16(ah[mt], bq, acc[mt][nt], 0, 0, 0);
        acc[mt][nt] = __builtin_amdgcn_mfma_f32_16x16x32_bf16(al[mt], bq, acc[mt][nt], 0, 0, 0);
      }
    }
    __builtin_amdgcn_s_setprio(0);
  };

  bf16x8 Ah0[4], Al0[4], Ah1[4], Al1[4];
  LOADA(Ah0, Al0, 0);
  STAGEB(0, 0);
  STAGEB(1, 1);
  for (int kt = 0; kt < 14; kt += 2) {
    SBAR();
    LOADA(Ah1, Al1, kt + 1);
    STAGEB(kt + 2, (kt + 2) % 3);
    VMCNT(12);
    SBAR();
    COMPUTE(Ah0, Al0, kt % 3);
    SBAR();
    LOADA(Ah0, Al0, kt + 2);
    STAGEB(kt + 3, (kt + 3) % 3);
    VMCNT(12);
    SBAR();
    COMPUTE(Ah1, Al1, (kt + 1) % 3);
  }
  SBAR();
  LOADA(Ah1, Al1, 15);
  VMCNT(10);
  SBAR();
  COMPUTE(Ah0, Al0, 2);
  SBAR();
  VMCNT(0);
  SBAR();
  COMPUTE(Ah1, Al1, 0);

  __syncthreads();
  float* smf = (float*)sm;
  float bi[4];
  #pragma unroll
  for (int nt = 0; nt < 4; ++nt) bi[nt] = b1[nbase + wn + (nt << 4) + lr];
  #pragma unroll
  for (int mt = 0; mt < 4; ++mt) {
    #pragma unroll
    for (int nt = 0; nt < 4; ++nt) {
      f32x4 v = acc[mt][nt];
      #pragma unroll
      for (int rr = 0; rr < 4; ++rr)
        smf[wv * 1088 + ((lg << 2) + rr) * 68 + (nt << 4) + lr] = v[rr] + bi[nt];
    }
    #pragma unroll
    for (int p = 0; p < 4; ++p) {
      int row = (p << 2) + (ln >> 4);
      int pos = tok0 + wm + (mt << 4) + row;
      if (pos >= n0) {
        f32x4 vv = *(const f32x4*)&smf[wv * 1088 + row * 68 + ((ln & 15) << 2)];
        *(f32x4*)&h32[(size_t)perm[pos] * DHID + nbase + wn + ((ln & 15) << 2)] = vv;
      }
    }
  }
}

// ---------------- DWConv3x3 + bias + exact GELU + gate2 partials ------------
// block=(dc,b): 32-d chunk, full image in 4 strips of 8 rows; 10-row tiles
// (incl. halo) DMA'd via global_load_lds, double-buffered, counted vmcnt.
__launch_bounds__(256, 2)
__global__ void k_conv(const float* __restrict__ h32, const float* __restrict__ zbuf,
                       const float* __restrict__ dww, const float* __restrict__ dwb,
                       const float* __restrict__ wg2,
                       unsigned short* __restrict__ hb, float* __restrict__ part) {
  __shared__ float4v tile[2][10][32][8];   // 80 KiB
  const int dc = blockIdx.x & 63;
  const int b  = blockIdx.x >> 6;
  const int t = threadIdx.x, wv = t >> 6, ln = t & 63;
  const int d0 = dc * 32;
  const int dl4 = t & 7, xq = t >> 3;

  auto STAGE = [&](int s, int db) {   // exactly 10 GLDS per wave
    const int y0 = s * 8;
    #pragma unroll
    for (int i = 0; i < 10; ++i) {
      int gi = wv * 10 + i;
      int ry = gi >> 2, qq = gi & 3;
      int y = y0 - 1 + ry;
      int sxq = qq * 8 + (ln >> 3);
      const float* src = (y >= 0 && y < 32)
        ? &h32[(size_t)((b << 10) + y * 32 + sxq) * DHID + d0 + (ln & 7) * 4]
        : &zbuf[ln * 4];
      GLDS16(src, &tile[db][ry][qq * 8][0]);
    }
  };

  const int d = d0 + dl4 * 4;
  float4v kk[9];
  #pragma unroll
  for (int i = 0; i < 9; ++i) {
    kk[i][0] = dww[(d + 0) * 9 + i]; kk[i][1] = dww[(d + 1) * 9 + i];
    kk[i][2] = dww[(d + 2) * 9 + i]; kk[i][3] = dww[(d + 3) * 9 + i];
  }
  const float4v bias = *(const float4v*)&dwb[d];
  float4v g0v, g1v;
  #pragma unroll
  for (int j = 0; j < 4; ++j) { g0v[j] = wg2[(d + j) * 2]; g1v[j] = wg2[(d + j) * 2 + 1]; }

  STAGE(0, 0);
  for (int s = 0; s < 4; ++s) {
    if (s < 3) {
      STAGE(s + 1, (s + 1) & 1);
      VMCNT(10);                      // strip s fully arrived (+ prior stores)
    } else {
      VMCNT(0);
    }
    SBAR();
    const int db = s & 1, y0 = s * 8;
    #pragma unroll
    for (int yy = 0; yy < 8; ++yy) {
      float4v sum = bias;
      #pragma unroll
      for (int dy = 0; dy < 3; ++dy)
        #pragma unroll
        for (int dx = 0; dx < 3; ++dx) {
          int xs = xq + dx - 1;
          if (xs >= 0 && xs < 32) {
            float4v v = tile[db][yy + dy][xs][dl4];
            float4v k = kk[dy * 3 + dx];
            sum[0] += v[0] * k[0]; sum[1] += v[1] * k[1];
            sum[2] += v[2] * k[2]; sum[3] += v[3] * k[3];
          }
        }
      float4v gg;
      #pragma unroll
      for (int j = 0; j < 4; ++j)
        gg[j] = 0.5f * sum[j] * (1.0f + erff(sum[j] * 0.70710678118654752f));  // exact
      int tok = (b << 10) + (y0 + yy) * 32 + xq;
      ushort4v hv;
      #pragma unroll
      for (int j = 0; j < 4; ++j) hv[j] = f2bf(gg[j]);
      *(ushort4v*)&hb[(size_t)tok * DHID + d] = hv;
      float p0 = gg[0] * g0v[0] + gg[1] * g0v[1] + gg[2] * g0v[2] + gg[3] * g0v[3];
      float p1 = gg[0] * g1v[0] + gg[1] * g1v[1] + gg[2] * g1v[2] + gg[3] * g1v[3];
      p0 += __shfl_xor(p0, 1); p0 += __shfl_xor(p0, 2); p0 += __shfl_xor(p0, 4);
      p1 += __shfl_xor(p1, 1); p1 += __shfl_xor(p1, 2); p1 += __shfl_xor(p1, 4);
      if (dl4 == 0) {
        part[(size_t)tok * 128 + dc] = p0;
        part[(size_t)tok * 128 + 64 + dc] = p1;
      }
    }
    SBAR();   // all waves done reading tile[db] before STAGE(s+2) overwrites
  }
}

// ------------------------- gate 2 reduce (wave per token) -------------------
__global__ void k_gate2(const float* __restrict__ part, unsigned char* __restrict__ pick2) {
  int tok = blockIdx.x * 4 + (threadIdx.x >> 6);
  int l = threadIdx.x & 63;
  const float* pr = part + (size_t)tok * 128;
  float s0 = pr[l], s1 = pr[64 + l];
  for (int m = 32; m; m >>= 1) { s0 += __shfl_xor(s0, m); s1 += __shfl_xor(s1, m); }
  if (l == 0) pick2[tok] = (s0 >= s1) ? 0 : 1;
}

// ------------------------- fc2 E0/E1: BK=64, A reg, B pipelined -------------
template <int EXPERT>
__launch_bounds__(256, 3)
__global__ void k_fc2_e(const unsigned short* __restrict__ hb,
                        const unsigned short* __restrict__ wb,
                        const float* __restrict__ bias_v,
                        const int* __restrict__ perm, const int* __restrict__ n0buf,
                        float* __restrict__ out) {
  __shared__ unsigned short sm[24576];   // 48 KiB
  const int n0 = n0buf[0];
  const int t = threadIdx.x, wv = t >> 6, ln = t & 63;
  const int lr = ln & 15, lg = ln >> 4;
  const int g = blockIdx.x, q = g >> 3;
  const int tok0 = ((g & 7) + ((q >> 2) << 3)) * 128;
  const int nbase = (q & 3) * 128;
  if (EXPERT == 0) { if (tok0 >= n0) return; }
  else             { if (tok0 + 128 <= n0) return; }
  const int wm = (wv >> 1) * 64, wn = (wv & 1) * 64;

  int rowoff[4];
  #pragma unroll
  for (int mt = 0; mt < 4; ++mt)
    rowoff[mt] = perm[tok0 + wm + (mt << 4) + lr] * DHID + (lg << 3);

  const int swsrc = (((ln & 3) ^ ((ln >> 3) & 3)) << 3);
  const int swrd  = ((lg ^ ((lr >> 1) & 3)) << 3);

  f32x4 acc[4][4];
  #pragma unroll
  for (int i = 0; i < 4; ++i)
    #pragma unroll
    for (int j = 0; j < 4; ++j) acc[i][j] = f32x4{0.f, 0.f, 0.f, 0.f};

  auto STAGEB = [&](int kt, int db) {   // 4 GLDS per wave
    #pragma unroll
    for (int ks = 0; ks < 2; ++ks) {
      const int k0 = kt * 64 + ks * 32;
      #pragma unroll
      for (int s = 0; s < 2; ++s) {
        const int rowblk = s * 4 + wv;
        size_t gb = (size_t)(nbase + (rowblk << 4) + (ln >> 2)) * DHID + k0 + swsrc;
        GLDS16(wb + gb, &sm[db * 8192 + ks * 4096 + (rowblk << 9)]);
      }
    }
  };
  auto LOADA = [&](bf16x8 (&a)[8], int kt) {
    #pragma unroll
    for (int ks = 0; ks < 2; ++ks) {
      const int k0 = kt * 64 + ks * 32;
      #pragma unroll
      for (int mt = 0; mt < 4; ++mt)
        a[ks * 4 + mt] = *(const bf16x8*)&hb[rowoff[mt] + k0];
    }
  };
  auto COMPUTE = [&](const bf16x8 (&a)[8], int db) {
    __builtin_amdgcn_s_setprio(1);
    #pragma unroll
    for (int ks = 0; ks < 2; ++ks) {
      #pragma unroll
      for (int nt = 0; nt < 4; ++nt) {
        bf16x8 bf = *(const bf16x8*)&sm[db * 8192 + ks * 4096 + (wn + (nt << 4) + lr) * 32 + swrd];
        #pragma unroll
        for (int mt = 0; mt < 4; ++mt)
          acc[mt][nt] = __builtin_amdgcn_mfma_f32_16x16x32_bf16(a[ks * 4 + mt], bf, acc[mt][nt], 0, 0, 0);
      }
    }
    __builtin_amdgcn_s_setprio(0);
  };

  bf16x8 A0[8], A1[8];
  LOADA(A0, 0);
  STAGEB(0, 0);
  STAGEB(1, 1);
  for (int kt = 0; kt < 30; kt += 2) {
    SBAR();
    LOADA(A1, kt + 1);
    STAGEB(kt + 2, (kt + 2) % 3);
    VMCNT(16);
    SBAR();
    COMPUTE(A0, kt % 3);
    SBAR();
    LOADA(A0, kt + 2);
    STAGEB(kt + 3, (kt + 3) % 3);
    VMCNT(16);
    SBAR();
    COMPUTE(A1, (kt + 1) % 3);
  }
  SBAR();
  LOADA(A1, 31);
  VMCNT(12);
  SBAR();
  COMPUTE(A0, 0);
  SBAR();
  VMCNT(0);
  SBAR();
  COMPUTE(A1, 1);

  __syncthreads();
  float* smf = (float*)sm;
  float bi[4];
  #pragma unroll
  for (int nt = 0; nt < 4; ++nt) bi[nt] = bias_v[nbase + wn + (nt << 4) + lr];
  #pragma unroll
  for (int mt = 0; mt < 4; ++mt) {
    #pragma unroll
    for (int nt = 0; nt < 4; ++nt) {
      f32x4 v = acc[mt][nt];
      #pragma unroll
      for (int rr = 0; rr < 4; ++rr)
        smf[wv * 1088 + ((lg << 2) + rr) * 68 + (nt << 4) + lr] = v[rr] + bi[nt];
    }
    #pragma unroll
    for (int p = 0; p < 4; ++p) {
      int row = (p << 2) + (ln >> 4);
      int pos = tok0 + wm + (mt << 4) + row;
      bool store = (EXPERT == 0) ? (pos < n0) : (pos >= n0);
      if (store) {
        f32x4 vv = *(const f32x4*)&smf[wv * 1088 + row * 68 + ((ln & 15) << 2)];
        *(f32x4*)&out[(size_t)perm[pos] * CIN + nbase + wn + ((ln & 15) << 2)] = vv;
      }
    }
  }
}

// ---------------------------------------------------------------------------
extern "C" void kernel_launch(void* const* d_in, const int* in_sizes, int n_in,
                              void* d_out, int out_size, void* d_ws, size_t ws_size,
                              hipStream_t stream) {
  (void)in_sizes; (void)n_in; (void)out_size; (void)ws_size;
  const float* x   = (const float*)d_in[0];
  const float* wg1 = (const float*)d_in[3];
  const float* w0  = (const float*)d_in[4];
  const float* b0  = (const float*)d_in[5];
  const float* w1  = (const float*)d_in[6];
  const float* b1  = (const float*)d_in[7];
  const float* dww = (const float*)d_in[8];
  const float* dwb = (const float*)d_in[9];
  const float* wg2 = (const float*)d_in[10];
  const float* w20 = (const float*)d_in[11];
  const float* b20 = (const float*)d_in[12];
  const float* w21 = (const float*)d_in[13];
  const float* b21 = (const float*)d_in[14];
  float* out = (float*)d_out;

  char* ws = (char*)d_ws;
  const size_t MB2 = 1u << 21;
  unsigned short* w0hi = (unsigned short*)(ws + 0 * MB2);
  unsigned short* w0lo = (unsigned short*)(ws + 1 * MB2);
  unsigned short* w1q  = (unsigned short*)(ws + 2 * MB2);
  unsigned short* w20b = (unsigned short*)(ws + 3 * MB2);
  unsigned short* w21b = (unsigned short*)(ws + 4 * MB2);
  char* p = ws + 5 * MB2;
  unsigned short* xhi = (unsigned short*)p;            p += (size_t)TOKS * CIN * 2;
  unsigned short* xlo = (unsigned short*)p;            p += (size_t)TOKS * CIN * 2;
  unsigned char* pick1 = (unsigned char*)p;            p += 65536;
  unsigned char* pick2 = (unsigned char*)p;            p += 65536;
  int* perm1 = (int*)p;                                p += TOKS * 4;
  int* perm2 = (int*)p;                                p += TOKS * 4;
  int* n0a   = (int*)p;                                p += 256;
  int* n0b   = (int*)p;                                p += 256;
  float* zbuf = (float*)p;                             p += 4096;
  float* part = (float*)p;                             p += (size_t)TOKS * 128 * 4;
  float* h32  = (float*)p;                             p += (size_t)TOKS * DHID * 4;
  unsigned short* hb = (unsigned short*)p;             // +64 MiB; total ~245 MiB

  hipMemsetAsync(zbuf, 0, 4096, stream);
  k_prep <<<8192, 256, 0, stream>>>(w0, w1, w20, w21, w0hi, w0lo, w1q, w20b, w21b,
                                    x, wg1, xhi, xlo, pick1);
  k_scan <<<1, 1024, 0, stream>>>(pick1, perm1, n0a);
  k_fc1_e0<<<2048, 256, 0, stream>>>(xhi, xlo, w0hi, w0lo, b0, perm1, n0a, h32);
  k_fc1_e1<<<2048, 256, 0, stream>>>(xhi, xlo, w1q, b1, perm1, n0a, h32);
  k_conv <<<1024, 256, 0, stream>>>(h32, zbuf, dww, dwb, wg2, hb, part);
  k_gate2<<<4096, 256, 0, stream>>>(part, pick2);
  k_scan <<<1, 1024, 0, stream>>>(pick2, perm2, n0b);
  k_fc2_e<0><<<512, 256, 0, stream>>>(hb, w20b, b20, perm2, n0b, out);
  k_fc2_e<1><<<512, 256, 0, stream>>>(hb, w21b, b21, perm2, n0b, out);
}

// Round 7
// 427.656 us; speedup vs baseline: 1.6156x; 1.6156x over previous
//
#include <hip/hip_runtime.h>
#include <hip/hip_bf16.h>

// ---------------------------------------------------------------------------
// Mlp_FMoE: fc1(MoE 2-expert top-1) -> DWConv3x3 -> GELU(exact) -> fc2(MoE)
// B=16 N=1024 C=512 Dh=2048 H=W=32, fp32 in/out.
// R7: revert launch_bounds to (256,2) everywhere (R6's (256,3/4) capped the
//     unified VGPR+AGPR file -> spills -> 647MB scratch writes, fc1_e1 411us).
//     Keep R6 conv (DMA strips) + merged prep + counted-vmcnt GEMMs.
// ---------------------------------------------------------------------------

#define TOKS  16384
#define CIN   512
#define DHID  2048

typedef __attribute__((ext_vector_type(8))) __bf16 bf16x8;
typedef __attribute__((ext_vector_type(4))) float  f32x4;
typedef __attribute__((ext_vector_type(4))) float  float4v;
typedef __attribute__((ext_vector_type(4))) unsigned short ushort4v;
typedef __attribute__((ext_vector_type(8))) unsigned short ushort8;

__device__ __forceinline__ unsigned short f2bf(float f) {
  union { float f; unsigned int u; } a; a.f = f;
  unsigned int u = a.u;
  unsigned int r = u + 0x7FFFu + ((u >> 16) & 1u);   // RNE
  return (unsigned short)(r >> 16);
}
__device__ __forceinline__ float bf2f(unsigned short h) {
  union { unsigned int u; float f; } a; a.u = ((unsigned int)h) << 16;
  return a.f;
}

// shift_quant: sign(w)*2^clip(round(log2(|w|+1e-12)),-14,0).
// round(log2(aw)) == e + (mantissa > sqrt(2)); exact via mantissa bit test.
__device__ __forceinline__ float squant(float w) {
  if (w == 0.0f) return 0.0f;
  float aw = fabsf(w) + 1e-12f;                 // fp32 add, as reference
  union { float f; unsigned u; } a; a.f = aw;
  int e = (int)((a.u >> 23) & 0xFFu) - 127;
  unsigned frac = a.u & 0x7FFFFFu;
  int shift = e + (frac >= 0x3504F4u ? 1 : 0);  // frac of sqrt(2)
  shift = min(max(shift, -14), 0);
  union { unsigned u; float f; } q; q.u = (unsigned)(shift + 127) << 23;
  return (w > 0.0f) ? q.f : -q.f;
}

#define GLDS16(gp, lp) __builtin_amdgcn_global_load_lds(                      \
    (const __attribute__((address_space(1))) void*)(gp),                      \
    (__attribute__((address_space(3))) void*)(lp), 16, 0, 0)

#define SBAR()  { __builtin_amdgcn_s_barrier(); __builtin_amdgcn_sched_barrier(0); }
#define VMCNT(n) asm volatile("s_waitcnt vmcnt(" #n ")" ::: "memory")

// ------------- merged prep: weights (blocks<4096) + x split/gate1 -----------
__global__ void k_prep(const float* __restrict__ w0, const float* __restrict__ w1,
                       const float* __restrict__ w20, const float* __restrict__ w21,
                       unsigned short* __restrict__ w0hi, unsigned short* __restrict__ w0lo,
                       unsigned short* __restrict__ w1q, unsigned short* __restrict__ w20b,
                       unsigned short* __restrict__ w21b,
                       const float* __restrict__ x, const float* __restrict__ wg1,
                       unsigned short* __restrict__ xhi, unsigned short* __restrict__ xlo,
                       unsigned char* __restrict__ pick1) {
  __shared__ float wg[1024];
  const int t = threadIdx.x;
  if (blockIdx.x < 4096) {
    int i = blockIdx.x * 256 + t;
    float v = w0[i];
    unsigned short h = f2bf(v);
    w0hi[i] = h;
    w0lo[i] = f2bf(v - bf2f(h));
    w1q[i]  = f2bf(squant(w1[i]));
    w20b[i] = f2bf(w20[i]);
    w21b[i] = f2bf(squant(w21[i]));
    return;
  }
  const int bid = blockIdx.x - 4096;
  #pragma unroll
  for (int i = 0; i < 4; ++i) wg[t + i * 256] = wg1[t + i * 256];
  __syncthreads();
  const int tok = bid * 4 + (t >> 6);
  const int l = t & 63;
  const float* xr = x + (size_t)tok * CIN + l * 8;
  float4v v0 = *(const float4v*)xr;
  float4v v1 = *(const float4v*)(xr + 4);
  float s0 = 0.f, s1 = 0.f;
  ushort8 hv, lv;
  #pragma unroll
  for (int j = 0; j < 8; ++j) {
    float v = (j < 4) ? v0[j] : v1[j - 4];
    unsigned short h = f2bf(v);
    hv[j] = h;
    lv[j] = f2bf(v - bf2f(h));
    int c = l * 8 + j;
    s0 += v * wg[c * 2];
    s1 += v * wg[c * 2 + 1];
  }
  *(ushort8*)&xhi[(size_t)tok * CIN + l * 8] = hv;
  *(ushort8*)&xlo[(size_t)tok * CIN + l * 8] = lv;
  for (int m = 32; m; m >>= 1) { s0 += __shfl_xor(s0, m); s1 += __shfl_xor(s1, m); }
  if (l == 0) pick1[tok] = (s0 >= s1) ? 0 : 1;   // argmax==0 on tie
}

// --------------- stable partition: perm = [expert0 toks..., expert1 toks...]
__global__ void k_scan(const unsigned char* __restrict__ pick, int* __restrict__ perm,
                       int* __restrict__ n0buf) {
  __shared__ int wpre[17];
  const int t = threadIdx.x;            // 1024
  const int lane = t & 63, w = t >> 6;  // 16 waves
  unsigned char loc[16]; int c0 = 0;
  #pragma unroll
  for (int i = 0; i < 16; ++i) { loc[i] = pick[t * 16 + i]; c0 += (loc[i] == 0); }
  int s = c0;
  #pragma unroll
  for (int off = 1; off < 64; off <<= 1) {
    int v = __shfl_up(s, off);
    if (lane >= off) s += v;
  }
  if (lane == 63) wpre[w + 1] = s;
  if (t == 0) wpre[0] = 0;
  __syncthreads();
  if (t == 0) {
    for (int j = 1; j <= 16; ++j) wpre[j] += wpre[j - 1];
    n0buf[0] = wpre[16];
  }
  __syncthreads();
  int total0 = wpre[16];
  int pre0 = wpre[w] + s - c0;
  int pre1 = t * 16 - pre0;
  int p0 = pre0, p1 = total0 + pre1;
  #pragma unroll
  for (int i = 0; i < 16; ++i) {
    int tok = t * 16 + i;
    if (loc[i] == 0) perm[p0++] = tok; else perm[p1++] = tok;
  }
}

// ------------------------- fc1 E0 (dense expert, bf16x3) --------------------
__launch_bounds__(256, 2)
__global__ void k_fc1_e0(const unsigned short* __restrict__ xhi,
                         const unsigned short* __restrict__ xlo,
                         const unsigned short* __restrict__ w0hi,
                         const unsigned short* __restrict__ w0lo,
                         const float* __restrict__ b0,
                         const int* __restrict__ perm, const int* __restrict__ n0buf,
                         float* __restrict__ h32) {
  __shared__ unsigned short sm[24576];   // 48 KiB: 3 bufs x {w0hi,w0lo} x 4096
  const int n0 = n0buf[0];
  const int t = threadIdx.x, wv = t >> 6, ln = t & 63;
  const int lr = ln & 15, lg = ln >> 4;
  const int g = blockIdx.x, q = g >> 3;
  const int tok0 = ((g & 7) + ((q >> 4) << 3)) * 128;
  const int nbase = (q & 15) * 128;
  if (tok0 >= n0) return;
  const int wm = (wv >> 1) * 64, wn = (wv & 1) * 64;

  int rowoff[4];
  #pragma unroll
  for (int mt = 0; mt < 4; ++mt)
    rowoff[mt] = perm[tok0 + wm + (mt << 4) + lr] * CIN + (lg << 3);

  const int swsrc = (((ln & 3) ^ ((ln >> 3) & 3)) << 3);
  const int swrd  = ((lg ^ ((lr >> 1) & 3)) << 3);

  f32x4 acc[4][4];
  #pragma unroll
  for (int i = 0; i < 4; ++i)
    #pragma unroll
    for (int j = 0; j < 4; ++j) acc[i][j] = f32x4{0.f, 0.f, 0.f, 0.f};

  auto STAGEB = [&](int kt, int db) {   // 4 GLDS per wave
    const int k0 = kt * 32;
    #pragma unroll
    for (int s = 0; s < 2; ++s) {
      const int rowblk = s * 4 + wv;
      size_t gb = (size_t)(nbase + (rowblk << 4) + (ln >> 2)) * CIN + k0 + swsrc;
      GLDS16(w0hi + gb, &sm[db * 8192 + (rowblk << 9)]);
      GLDS16(w0lo + gb, &sm[db * 8192 + 4096 + (rowblk << 9)]);
    }
  };
  auto LOADA = [&](bf16x8 (&ah)[4], bf16x8 (&al)[4], int kt) {
    const int k0 = kt * 32;
    #pragma unroll
    for (int mt = 0; mt < 4; ++mt) {
      ah[mt] = *(const bf16x8*)&xhi[rowoff[mt] + k0];
      al[mt] = *(const bf16x8*)&xlo[rowoff[mt] + k0];
    }
  };
  auto COMPUTE = [&](const bf16x8 (&ah)[4], const bf16x8 (&al)[4], int db) {
    __builtin_amdgcn_s_setprio(1);
    #pragma unroll
    for (int nt = 0; nt < 4; ++nt) {
      int bb = db * 8192 + (wn + (nt << 4) + lr) * 32 + swrd;
      bf16x8 bh = *(const bf16x8*)&sm[bb];
      bf16x8 bl = *(const bf16x8*)&sm[bb + 4096];
      #pragma unroll
      for (int mt = 0; mt < 4; ++mt) {
        acc[mt][nt] = __builtin_amdgcn_mfma_f32_16x16x32_bf16(ah[mt], bh, acc[mt][nt], 0, 0, 0);
        acc[mt][nt] = __builtin_amdgcn_mfma_f32_16x16x32_bf16(al[mt], bh, acc[mt][nt], 0, 0, 0);
        acc[mt][nt] = __builtin_amdgcn_mfma_f32_16x16x32_bf16(ah[mt], bl, acc[mt][nt], 0, 0, 0);
      }
    }
    __builtin_amdgcn_s_setprio(0);
  };

  bf16x8 Ah0[4], Al0[4], Ah1[4], Al1[4];
  LOADA(Ah0, Al0, 0);
  STAGEB(0, 0);
  STAGEB(1, 1);
  for (int kt = 0; kt < 14; kt += 2) {
    SBAR();
    LOADA(Ah1, Al1, kt + 1);
    STAGEB(kt + 2, (kt + 2) % 3);
    VMCNT(16);
    SBAR();
    COMPUTE(Ah0, Al0, kt % 3);
    SBAR();
    LOADA(Ah0, Al0, kt + 2);
    STAGEB(kt + 3, (kt + 3) % 3);
    VMCNT(16);
    SBAR();
    COMPUTE(Ah1, Al1, (kt + 1) % 3);
  }
  SBAR();
  LOADA(Ah1, Al1, 15);
  VMCNT(12);
  SBAR();
  COMPUTE(Ah0, Al0, 2);
  SBAR();
  VMCNT(0);
  SBAR();
  COMPUTE(Ah1, Al1, 0);

  __syncthreads();
  float* smf = (float*)sm;
  float bi[4];
  #pragma unroll
  for (int nt = 0; nt < 4; ++nt) bi[nt] = b0[nbase + wn + (nt << 4) + lr];
  #pragma unroll
  for (int mt = 0; mt < 4; ++mt) {
    #pragma unroll
    for (int nt = 0; nt < 4; ++nt) {
      f32x4 v = acc[mt][nt];
      #pragma unroll
      for (int rr = 0; rr < 4; ++rr)
        smf[wv * 1088 + ((lg << 2) + rr) * 68 + (nt << 4) + lr] = v[rr] + bi[nt];
    }
    #pragma unroll
    for (int p = 0; p < 4; ++p) {
      int row = (p << 2) + (ln >> 4);
      int pos = tok0 + wm + (mt << 4) + row;
      if (pos < n0) {
        f32x4 vv = *(const f32x4*)&smf[wv * 1088 + row * 68 + ((ln & 15) << 2)];
        *(f32x4*)&h32[(size_t)perm[pos] * DHID + nbase + wn + ((ln & 15) << 2)] = vv;
      }
    }
  }
}

// ------------------------- fc1 E1 (shift expert, bf16x2) --------------------
__launch_bounds__(256, 2)
__global__ void k_fc1_e1(const unsigned short* __restrict__ xhi,
                         const unsigned short* __restrict__ xlo,
                         const unsigned short* __restrict__ w1q,
                         const float* __restrict__ b1,
                         const int* __restrict__ perm, const int* __restrict__ n0buf,
                         float* __restrict__ h32) {
  __shared__ unsigned short sm[12288];   // 24 KiB
  const int n0 = n0buf[0];
  const int t = threadIdx.x, wv = t >> 6, ln = t & 63;
  const int lr = ln & 15, lg = ln >> 4;
  const int g = blockIdx.x, q = g >> 3;
  const int tok0 = ((g & 7) + ((q >> 4) << 3)) * 128;
  const int nbase = (q & 15) * 128;
  if (tok0 + 128 <= n0) return;
  const int wm = (wv >> 1) * 64, wn = (wv & 1) * 64;

  int rowoff[4];
  #pragma unroll
  for (int mt = 0; mt < 4; ++mt)
    rowoff[mt] = perm[tok0 + wm + (mt << 4) + lr] * CIN + (lg << 3);

  const int swsrc = (((ln & 3) ^ ((ln >> 3) & 3)) << 3);
  const int swrd  = ((lg ^ ((lr >> 1) & 3)) << 3);

  f32x4 acc[4][4];
  #pragma unroll
  for (int i = 0; i < 4; ++i)
    #pragma unroll
    for (int j = 0; j < 4; ++j) acc[i][j] = f32x4{0.f, 0.f, 0.f, 0.f};

  auto STAGEB = [&](int kt, int db) {   // 2 GLDS per wave
    const int k0 = kt * 32;
    #pragma unroll
    for (int s = 0; s < 2; ++s) {
      const int rowblk = s * 4 + wv;
      size_t gb = (size_t)(nbase + (rowblk << 4) + (ln >> 2)) * CIN + k0 + swsrc;
      GLDS16(w1q + gb, &sm[db * 4096 + (rowblk << 9)]);
    }
  };
  auto LOADA = [&](bf16x8 (&ah)[4], bf16x8 (&al)[4], int kt) {
    const int k0 = kt * 32;
    #pragma unroll
    for (int mt = 0; mt < 4; ++mt) {
      ah[mt] = *(const bf16x8*)&xhi[rowoff[mt] + k0];
      al[mt] = *(const bf16x8*)&xlo[rowoff[mt] + k0];
    }
  };
  auto COMPUTE = [&](const bf16x8 (&ah)[4], const bf16x8 (&al)[4], int db) {
    __builtin_amdgcn_s_setprio(1);
    #pragma unroll
    for (int nt = 0; nt < 4; ++nt) {
      bf16x8 bq = *(const bf16x8*)&sm[db * 4096 + (wn + (nt << 4) + lr) * 32 + swrd];
      #pragma unroll
      for (int mt = 0; mt < 4; ++mt) {
        acc[mt][nt] = __builtin_amdgcn_mfma_f32_16x16x32_bf16(ah[mt], bq, acc[mt][nt], 0, 0, 0);
        acc[mt][nt] = __builtin_amdgcn_mfma_f32_16x16x32_bf16(al[mt], bq, acc[mt][nt], 0, 0, 0);
      }
    }
    __builtin_amdgcn_s_setprio(0);
  };

  bf16x8 Ah0[4], Al0[4], Ah1[4], Al1[4];
  LOADA(Ah0, Al0, 0);
  STAGEB(0, 0);
  STAGEB(1, 1);
  for (int kt = 0; kt < 14; kt += 2) {
    SBAR();
    LOADA(Ah1, Al1, kt + 1);
    STAGEB(kt + 2, (kt + 2) % 3);
    VMCNT(12);
    SBAR();
    COMPUTE(Ah0, Al0, kt % 3);
    SBAR();
    LOADA(Ah0, Al0, kt + 2);
    STAGEB(kt + 3, (kt + 3) % 3);
    VMCNT(12);
    SBAR();
    COMPUTE(Ah1, Al1, (kt + 1) % 3);
  }
  SBAR();
  LOADA(Ah1, Al1, 15);
  VMCNT(10);
  SBAR();
  COMPUTE(Ah0, Al0, 2);
  SBAR();
  VMCNT(0);
  SBAR();
  COMPUTE(Ah1, Al1, 0);

  __syncthreads();
  float* smf = (float*)sm;
  float bi[4];
  #pragma unroll
  for (int nt = 0; nt < 4; ++nt) bi[nt] = b1[nbase + wn + (nt << 4) + lr];
  #pragma unroll
  for (int mt = 0; mt < 4; ++mt) {
    #pragma unroll
    for (int nt = 0; nt < 4; ++nt) {
      f32x4 v = acc[mt][nt];
      #pragma unroll
      for (int rr = 0; rr < 4; ++rr)
        smf[wv * 1088 + ((lg << 2) + rr) * 68 + (nt << 4) + lr] = v[rr] + bi[nt];
    }
    #pragma unroll
    for (int p = 0; p < 4; ++p) {
      int row = (p << 2) + (ln >> 4);
      int pos = tok0 + wm + (mt << 4) + row;
      if (pos >= n0) {
        f32x4 vv = *(const f32x4*)&smf[wv * 1088 + row * 68 + ((ln & 15) << 2)];
        *(f32x4*)&h32[(size_t)perm[pos] * DHID + nbase + wn + ((ln & 15) << 2)] = vv;
      }
    }
  }
}

// ---------------- DWConv3x3 + bias + exact GELU + gate2 partials ------------
// block=(dc,b): 32-d chunk, full image in 4 strips of 8 rows; 10-row tiles
// (incl. halo) DMA'd via global_load_lds, double-buffered, counted vmcnt.
__launch_bounds__(256, 2)
__global__ void k_conv(const float* __restrict__ h32, const float* __restrict__ zbuf,
                       const float* __restrict__ dww, const float* __restrict__ dwb,
                       const float* __restrict__ wg2,
                       unsigned short* __restrict__ hb, float* __restrict__ part) {
  __shared__ float4v tile[2][10][32][8];   // 80 KiB
  const int dc = blockIdx.x & 63;
  const int b  = blockIdx.x >> 6;
  const int t = threadIdx.x, wv = t >> 6, ln = t & 63;
  const int d0 = dc * 32;
  const int dl4 = t & 7, xq = t >> 3;

  auto STAGE = [&](int s, int db) {   // exactly 10 GLDS per wave
    const int y0 = s * 8;
    #pragma unroll
    for (int i = 0; i < 10; ++i) {
      int gi = wv * 10 + i;
      int ry = gi >> 2, qq = gi & 3;
      int y = y0 - 1 + ry;
      int sxq = qq * 8 + (ln >> 3);
      const float* src = (y >= 0 && y < 32)
        ? &h32[(size_t)((b << 10) + y * 32 + sxq) * DHID + d0 + (ln & 7) * 4]
        : &zbuf[ln * 4];
      GLDS16(src, &tile[db][ry][qq * 8][0]);
    }
  };

  const int d = d0 + dl4 * 4;
  float4v kk[9];
  #pragma unroll
  for (int i = 0; i < 9; ++i) {
    kk[i][0] = dww[(d + 0) * 9 + i]; kk[i][1] = dww[(d + 1) * 9 + i];
    kk[i][2] = dww[(d + 2) * 9 + i]; kk[i][3] = dww[(d + 3) * 9 + i];
  }
  const float4v bias = *(const float4v*)&dwb[d];
  float4v g0v, g1v;
  #pragma unroll
  for (int j = 0; j < 4; ++j) { g0v[j] = wg2[(d + j) * 2]; g1v[j] = wg2[(d + j) * 2 + 1]; }

  STAGE(0, 0);
  for (int s = 0; s < 4; ++s) {
    if (s < 3) {
      STAGE(s + 1, (s + 1) & 1);
      VMCNT(10);                      // strip s fully arrived (+ prior stores)
    } else {
      VMCNT(0);
    }
    SBAR();
    const int db = s & 1, y0 = s * 8;
    #pragma unroll
    for (int yy = 0; yy < 8; ++yy) {
      float4v sum = bias;
      #pragma unroll
      for (int dy = 0; dy < 3; ++dy)
        #pragma unroll
        for (int dx = 0; dx < 3; ++dx) {
          int xs = xq + dx - 1;
          if (xs >= 0 && xs < 32) {
            float4v v = tile[db][yy + dy][xs][dl4];
            float4v k = kk[dy * 3 + dx];
            sum[0] += v[0] * k[0]; sum[1] += v[1] * k[1];
            sum[2] += v[2] * k[2]; sum[3] += v[3] * k[3];
          }
        }
      float4v gg;
      #pragma unroll
      for (int j = 0; j < 4; ++j)
        gg[j] = 0.5f * sum[j] * (1.0f + erff(sum[j] * 0.70710678118654752f));  // exact
      int tok = (b << 10) + (y0 + yy) * 32 + xq;
      ushort4v hv;
      #pragma unroll
      for (int j = 0; j < 4; ++j) hv[j] = f2bf(gg[j]);
      *(ushort4v*)&hb[(size_t)tok * DHID + d] = hv;
      float p0 = gg[0] * g0v[0] + gg[1] * g0v[1] + gg[2] * g0v[2] + gg[3] * g0v[3];
      float p1 = gg[0] * g1v[0] + gg[1] * g1v[1] + gg[2] * g1v[2] + gg[3] * g1v[3];
      p0 += __shfl_xor(p0, 1); p0 += __shfl_xor(p0, 2); p0 += __shfl_xor(p0, 4);
      p1 += __shfl_xor(p1, 1); p1 += __shfl_xor(p1, 2); p1 += __shfl_xor(p1, 4);
      if (dl4 == 0) {
        part[(size_t)tok * 128 + dc] = p0;
        part[(size_t)tok * 128 + 64 + dc] = p1;
      }
    }
    SBAR();   // all waves done reading tile[db] before STAGE(s+2) overwrites
  }
}

// ------------------------- gate 2 reduce (wave per token) -------------------
__global__ void k_gate2(const float* __restrict__ part, unsigned char* __restrict__ pick2) {
  int tok = blockIdx.x * 4 + (threadIdx.x >> 6);
  int l = threadIdx.x & 63;
  const float* pr = part + (size_t)tok * 128;
  float s0 = pr[l], s1 = pr[64 + l];
  for (int m = 32; m; m >>= 1) { s0 += __shfl_xor(s0, m); s1 += __shfl_xor(s1, m); }
  if (l == 0) pick2[tok] = (s0 >= s1) ? 0 : 1;
}

// ------------------------- fc2 E0/E1: BK=64, A reg, B pipelined -------------
template <int EXPERT>
__launch_bounds__(256, 2)
__global__ void k_fc2_e(const unsigned short* __restrict__ hb,
                        const unsigned short* __restrict__ wb,
                        const float* __restrict__ bias_v,
                        const int* __restrict__ perm, const int* __restrict__ n0buf,
                        float* __restrict__ out) {
  __shared__ unsigned short sm[24576];   // 48 KiB
  const int n0 = n0buf[0];
  const int t = threadIdx.x, wv = t >> 6, ln = t & 63;
  const int lr = ln & 15, lg = ln >> 4;
  const int g = blockIdx.x, q = g >> 3;
  const int tok0 = ((g & 7) + ((q >> 2) << 3)) * 128;
  const int nbase = (q & 3) * 128;
  if (EXPERT == 0) { if (tok0 >= n0) return; }
  else             { if (tok0 + 128 <= n0) return; }
  const int wm = (wv >> 1) * 64, wn = (wv & 1) * 64;

  int rowoff[4];
  #pragma unroll
  for (int mt = 0; mt < 4; ++mt)
    rowoff[mt] = perm[tok0 + wm + (mt << 4) + lr] * DHID + (lg << 3);

  const int swsrc = (((ln & 3) ^ ((ln >> 3) & 3)) << 3);
  const int swrd  = ((lg ^ ((lr >> 1) & 3)) << 3);

  f32x4 acc[4][4];
  #pragma unroll
  for (int i = 0; i < 4; ++i)
    #pragma unroll
    for (int j = 0; j < 4; ++j) acc[i][j] = f32x4{0.f, 0.f, 0.f, 0.f};

  auto STAGEB = [&](int kt, int db) {   // 4 GLDS per wave
    #pragma unroll
    for (int ks = 0; ks < 2; ++ks) {
      const int k0 = kt * 64 + ks * 32;
      #pragma unroll
      for (int s = 0; s < 2; ++s) {
        const int rowblk = s * 4 + wv;
        size_t gb = (size_t)(nbase + (rowblk << 4) + (ln >> 2)) * DHID + k0 + swsrc;
        GLDS16(wb + gb, &sm[db * 8192 + ks * 4096 + (rowblk << 9)]);
      }
    }
  };
  auto LOADA = [&](bf16x8 (&a)[8], int kt) {
    #pragma unroll
    for (int ks = 0; ks < 2; ++ks) {
      const int k0 = kt * 64 + ks * 32;
      #pragma unroll
      for (int mt = 0; mt < 4; ++mt)
        a[ks * 4 + mt] = *(const bf16x8*)&hb[rowoff[mt] + k0];
    }
  };
  auto COMPUTE = [&](const bf16x8 (&a)[8], int db) {
    __builtin_amdgcn_s_setprio(1);
    #pragma unroll
    for (int ks = 0; ks < 2; ++ks) {
      #pragma unroll
      for (int nt = 0; nt < 4; ++nt) {
        bf16x8 bf = *(const bf16x8*)&sm[db * 8192 + ks * 4096 + (wn + (nt << 4) + lr) * 32 + swrd];
        #pragma unroll
        for (int mt = 0; mt < 4; ++mt)
          acc[mt][nt] = __builtin_amdgcn_mfma_f32_16x16x32_bf16(a[ks * 4 + mt], bf, acc[mt][nt], 0, 0, 0);
      }
    }
    __builtin_amdgcn_s_setprio(0);
  };

  bf16x8 A0[8], A1[8];
  LOADA(A0, 0);
  STAGEB(0, 0);
  STAGEB(1, 1);
  for (int kt = 0; kt < 30; kt += 2) {
    SBAR();
    LOADA(A1, kt + 1);
    STAGEB(kt + 2, (kt + 2) % 3);
    VMCNT(16);
    SBAR();
    COMPUTE(A0, kt % 3);
    SBAR();
    LOADA(A0, kt + 2);
    STAGEB(kt + 3, (kt + 3) % 3);
    VMCNT(16);
    SBAR();
    COMPUTE(A1, (kt + 1) % 3);
  }
  SBAR();
  LOADA(A1, 31);
  VMCNT(12);
  SBAR();
  COMPUTE(A0, 0);
  SBAR();
  VMCNT(0);
  SBAR();
  COMPUTE(A1, 1);

  __syncthreads();
  float* smf = (float*)sm;
  float bi[4];
  #pragma unroll
  for (int nt = 0; nt < 4; ++nt) bi[nt] = bias_v[nbase + wn + (nt << 4) + lr];
  #pragma unroll
  for (int mt = 0; mt < 4; ++mt) {
    #pragma unroll
    for (int nt = 0; nt < 4; ++nt) {
      f32x4 v = acc[mt][nt];
      #pragma unroll
      for (int rr = 0; rr < 4; ++rr)
        smf[wv * 1088 + ((lg << 2) + rr) * 68 + (nt << 4) + lr] = v[rr] + bi[nt];
    }
    #pragma unroll
    for (int p = 0; p < 4; ++p) {
      int row = (p << 2) + (ln >> 4);
      int pos = tok0 + wm + (mt << 4) + row;
      bool store = (EXPERT == 0) ? (pos < n0) : (pos >= n0);
      if (store) {
        f32x4 vv = *(const f32x4*)&smf[wv * 1088 + row * 68 + ((ln & 15) << 2)];
        *(f32x4*)&out[(size_t)perm[pos] * CIN + nbase + wn + ((ln & 15) << 2)] = vv;
      }
    }
  }
}

// ---------------------------------------------------------------------------
extern "C" void kernel_launch(void* const* d_in, const int* in_sizes, int n_in,
                              void* d_out, int out_size, void* d_ws, size_t ws_size,
                              hipStream_t stream) {
  (void)in_sizes; (void)n_in; (void)out_size; (void)ws_size;
  const float* x   = (const float*)d_in[0];
  const float* wg1 = (const float*)d_in[3];
  const float* w0  = (const float*)d_in[4];
  const float* b0  = (const float*)d_in[5];
  const float* w1  = (const float*)d_in[6];
  const float* b1  = (const float*)d_in[7];
  const float* dww = (const float*)d_in[8];
  const float* dwb = (const float*)d_in[9];
  const float* wg2 = (const float*)d_in[10];
  const float* w20 = (const float*)d_in[11];
  const float* b20 = (const float*)d_in[12];
  const float* w21 = (const float*)d_in[13];
  const float* b21 = (const float*)d_in[14];
  float* out = (float*)d_out;

  char* ws = (char*)d_ws;
  const size_t MB2 = 1u << 21;
  unsigned short* w0hi = (unsigned short*)(ws + 0 * MB2);
  unsigned short* w0lo = (unsigned short*)(ws + 1 * MB2);
  unsigned short* w1q  = (unsigned short*)(ws + 2 * MB2);
  unsigned short* w20b = (unsigned short*)(ws + 3 * MB2);
  unsigned short* w21b = (unsigned short*)(ws + 4 * MB2);
  char* p = ws + 5 * MB2;
  unsigned short* xhi = (unsigned short*)p;            p += (size_t)TOKS * CIN * 2;
  unsigned short* xlo = (unsigned short*)p;            p += (size_t)TOKS * CIN * 2;
  unsigned char* pick1 = (unsigned char*)p;            p += 65536;
  unsigned char* pick2 = (unsigned char*)p;            p += 65536;
  int* perm1 = (int*)p;                                p += TOKS * 4;
  int* perm2 = (int*)p;                                p += TOKS * 4;
  int* n0a   = (int*)p;                                p += 256;
  int* n0b   = (int*)p;                                p += 256;
  float* zbuf = (float*)p;                             p += 4096;
  float* part = (float*)p;                             p += (size_t)TOKS * 128 * 4;
  float* h32  = (float*)p;                             p += (size_t)TOKS * DHID * 4;
  unsigned short* hb = (unsigned short*)p;             // +64 MiB; total ~245 MiB

  hipMemsetAsync(zbuf, 0, 4096, stream);
  k_prep <<<8192, 256, 0, stream>>>(w0, w1, w20, w21, w0hi, w0lo, w1q, w20b, w21b,
                                    x, wg1, xhi, xlo, pick1);
  k_scan <<<1, 1024, 0, stream>>>(pick1, perm1, n0a);
  k_fc1_e0<<<2048, 256, 0, stream>>>(xhi, xlo, w0hi, w0lo, b0, perm1, n0a, h32);
  k_fc1_e1<<<2048, 256, 0, stream>>>(xhi, xlo, w1q, b1, perm1, n0a, h32);
  k_conv <<<1024, 256, 0, stream>>>(h32, zbuf, dww, dwb, wg2, hb, part);
  k_gate2<<<4096, 256, 0, stream>>>(part, pick2);
  k_scan <<<1, 1024, 0, stream>>>(pick2, perm2, n0b);
  k_fc2_e<0><<<512, 256, 0, stream>>>(hb, w20b, b20, perm2, n0b, out);
  k_fc2_e<1><<<512, 256, 0, stream>>>(hb, w21b, b21, perm2, n0b, out);
}

// Round 8
// 401.809 us; speedup vs baseline: 1.7195x; 1.0643x over previous
//
#include <hip/hip_runtime.h>
#include <hip/hip_bf16.h>

// ---------------------------------------------------------------------------
// Mlp_FMoE: fc1(MoE 2-expert top-1) -> DWConv3x3 -> GELU(exact) -> fc2(MoE)
// B=16 N=1024 C=512 Dh=2048 H=W=32, fp32 in/out.
// R8: conv back to R5 high-occupancy structure + A-S 7.1.26 fast erf
//     (1.5e-7, rcp+exp2+5FMA) + part[] transposed to [128][TOKS] (kills
//     cross-block 4B write interleave, 131->75MB). GEMMs unchanged from R7.
// ---------------------------------------------------------------------------

#define TOKS  16384
#define CIN   512
#define DHID  2048

typedef __attribute__((ext_vector_type(8))) __bf16 bf16x8;
typedef __attribute__((ext_vector_type(4))) float  f32x4;
typedef __attribute__((ext_vector_type(4))) float  float4v;
typedef __attribute__((ext_vector_type(4))) unsigned short ushort4v;
typedef __attribute__((ext_vector_type(8))) unsigned short ushort8;

__device__ __forceinline__ unsigned short f2bf(float f) {
  union { float f; unsigned int u; } a; a.f = f;
  unsigned int u = a.u;
  unsigned int r = u + 0x7FFFu + ((u >> 16) & 1u);   // RNE
  return (unsigned short)(r >> 16);
}
__device__ __forceinline__ float bf2f(unsigned short h) {
  union { unsigned int u; float f; } a; a.u = ((unsigned int)h) << 16;
  return a.f;
}

// shift_quant: sign(w)*2^clip(round(log2(|w|+1e-12)),-14,0).
// round(log2(aw)) == e + (mantissa > sqrt(2)); exact via mantissa bit test.
__device__ __forceinline__ float squant(float w) {
  if (w == 0.0f) return 0.0f;
  float aw = fabsf(w) + 1e-12f;                 // fp32 add, as reference
  union { float f; unsigned u; } a; a.f = aw;
  int e = (int)((a.u >> 23) & 0xFFu) - 127;
  unsigned frac = a.u & 0x7FFFFFu;
  int shift = e + (frac >= 0x3504F4u ? 1 : 0);  // frac of sqrt(2)
  shift = min(max(shift, -14), 0);
  union { unsigned u; float f; } q; q.u = (unsigned)(shift + 127) << 23;
  return (w > 0.0f) ? q.f : -q.f;
}

// gelu via Abramowitz-Stegun 7.1.26 erf (|eps| <= 1.5e-7):
// erf(z) = 1 - (a1 t + .. + a5 t^5) exp(-z^2), t = 1/(1+0.3275911 z), z>=0
__device__ __forceinline__ float gelu_fast(float s) {
  float z = fabsf(s) * 0.70710678118654752f;
  float zz = z * z;
#if __has_builtin(__builtin_amdgcn_exp2f)
  float e = __builtin_amdgcn_exp2f(zz * -1.4426950408889634f);
#else
  float e = exp2f(zz * -1.4426950408889634f);
#endif
  float d = fmaf(0.3275911f, z, 1.0f);
#if __has_builtin(__builtin_amdgcn_rcpf)
  float t = __builtin_amdgcn_rcpf(d);
#else
  float t = 1.0f / d;
#endif
  float p = fmaf(1.061405429f, t, -1.453152027f);
  p = fmaf(p, t, 1.421413741f);
  p = fmaf(p, t, -0.284496736f);
  p = fmaf(p, t, 0.254829592f);
  p = p * t;
  float erfz = fmaf(-p, e, 1.0f);
  float er = (s < 0.0f) ? -erfz : erfz;
  return 0.5f * s * (1.0f + er);
}

#define GLDS16(gp, lp) __builtin_amdgcn_global_load_lds(                      \
    (const __attribute__((address_space(1))) void*)(gp),                      \
    (__attribute__((address_space(3))) void*)(lp), 16, 0, 0)

#define SBAR()  { __builtin_amdgcn_s_barrier(); __builtin_amdgcn_sched_barrier(0); }
#define VMCNT(n) asm volatile("s_waitcnt vmcnt(" #n ")" ::: "memory")

// ------------- merged prep: weights (blocks<4096) + x split/gate1 -----------
__global__ void k_prep(const float* __restrict__ w0, const float* __restrict__ w1,
                       const float* __restrict__ w20, const float* __restrict__ w21,
                       unsigned short* __restrict__ w0hi, unsigned short* __restrict__ w0lo,
                       unsigned short* __restrict__ w1q, unsigned short* __restrict__ w20b,
                       unsigned short* __restrict__ w21b,
                       const float* __restrict__ x, const float* __restrict__ wg1,
                       unsigned short* __restrict__ xhi, unsigned short* __restrict__ xlo,
                       unsigned char* __restrict__ pick1) {
  __shared__ float wg[1024];
  const int t = threadIdx.x;
  if (blockIdx.x < 4096) {
    int i = blockIdx.x * 256 + t;
    float v = w0[i];
    unsigned short h = f2bf(v);
    w0hi[i] = h;
    w0lo[i] = f2bf(v - bf2f(h));
    w1q[i]  = f2bf(squant(w1[i]));
    w20b[i] = f2bf(w20[i]);
    w21b[i] = f2bf(squant(w21[i]));
    return;
  }
  const int bid = blockIdx.x - 4096;
  #pragma unroll
  for (int i = 0; i < 4; ++i) wg[t + i * 256] = wg1[t + i * 256];
  __syncthreads();
  const int tok = bid * 4 + (t >> 6);
  const int l = t & 63;
  const float* xr = x + (size_t)tok * CIN + l * 8;
  float4v v0 = *(const float4v*)xr;
  float4v v1 = *(const float4v*)(xr + 4);
  float s0 = 0.f, s1 = 0.f;
  ushort8 hv, lv;
  #pragma unroll
  for (int j = 0; j < 8; ++j) {
    float v = (j < 4) ? v0[j] : v1[j - 4];
    unsigned short h = f2bf(v);
    hv[j] = h;
    lv[j] = f2bf(v - bf2f(h));
    int c = l * 8 + j;
    s0 += v * wg[c * 2];
    s1 += v * wg[c * 2 + 1];
  }
  *(ushort8*)&xhi[(size_t)tok * CIN + l * 8] = hv;
  *(ushort8*)&xlo[(size_t)tok * CIN + l * 8] = lv;
  for (int m = 32; m; m >>= 1) { s0 += __shfl_xor(s0, m); s1 += __shfl_xor(s1, m); }
  if (l == 0) pick1[tok] = (s0 >= s1) ? 0 : 1;   // argmax==0 on tie
}

// --------------- stable partition: perm = [expert0 toks..., expert1 toks...]
__global__ void k_scan(const unsigned char* __restrict__ pick, int* __restrict__ perm,
                       int* __restrict__ n0buf) {
  __shared__ int wpre[17];
  const int t = threadIdx.x;            // 1024
  const int lane = t & 63, w = t >> 6;  // 16 waves
  unsigned char loc[16]; int c0 = 0;
  #pragma unroll
  for (int i = 0; i < 16; ++i) { loc[i] = pick[t * 16 + i]; c0 += (loc[i] == 0); }
  int s = c0;
  #pragma unroll
  for (int off = 1; off < 64; off <<= 1) {
    int v = __shfl_up(s, off);
    if (lane >= off) s += v;
  }
  if (lane == 63) wpre[w + 1] = s;
  if (t == 0) wpre[0] = 0;
  __syncthreads();
  if (t == 0) {
    for (int j = 1; j <= 16; ++j) wpre[j] += wpre[j - 1];
    n0buf[0] = wpre[16];
  }
  __syncthreads();
  int total0 = wpre[16];
  int pre0 = wpre[w] + s - c0;
  int pre1 = t * 16 - pre0;
  int p0 = pre0, p1 = total0 + pre1;
  #pragma unroll
  for (int i = 0; i < 16; ++i) {
    int tok = t * 16 + i;
    if (loc[i] == 0) perm[p0++] = tok; else perm[p1++] = tok;
  }
}

// ------------------------- fc1 E0 (dense expert, bf16x3) --------------------
__launch_bounds__(256, 2)
__global__ void k_fc1_e0(const unsigned short* __restrict__ xhi,
                         const unsigned short* __restrict__ xlo,
                         const unsigned short* __restrict__ w0hi,
                         const unsigned short* __restrict__ w0lo,
                         const float* __restrict__ b0,
                         const int* __restrict__ perm, const int* __restrict__ n0buf,
                         float* __restrict__ h32) {
  __shared__ unsigned short sm[24576];   // 48 KiB: 3 bufs x {w0hi,w0lo} x 4096
  const int n0 = n0buf[0];
  const int t = threadIdx.x, wv = t >> 6, ln = t & 63;
  const int lr = ln & 15, lg = ln >> 4;
  const int g = blockIdx.x, q = g >> 3;
  const int tok0 = ((g & 7) + ((q >> 4) << 3)) * 128;
  const int nbase = (q & 15) * 128;
  if (tok0 >= n0) return;
  const int wm = (wv >> 1) * 64, wn = (wv & 1) * 64;

  int rowoff[4];
  #pragma unroll
  for (int mt = 0; mt < 4; ++mt)
    rowoff[mt] = perm[tok0 + wm + (mt << 4) + lr] * CIN + (lg << 3);

  const int swsrc = (((ln & 3) ^ ((ln >> 3) & 3)) << 3);
  const int swrd  = ((lg ^ ((lr >> 1) & 3)) << 3);

  f32x4 acc[4][4];
  #pragma unroll
  for (int i = 0; i < 4; ++i)
    #pragma unroll
    for (int j = 0; j < 4; ++j) acc[i][j] = f32x4{0.f, 0.f, 0.f, 0.f};

  auto STAGEB = [&](int kt, int db) {   // 4 GLDS per wave
    const int k0 = kt * 32;
    #pragma unroll
    for (int s = 0; s < 2; ++s) {
      const int rowblk = s * 4 + wv;
      size_t gb = (size_t)(nbase + (rowblk << 4) + (ln >> 2)) * CIN + k0 + swsrc;
      GLDS16(w0hi + gb, &sm[db * 8192 + (rowblk << 9)]);
      GLDS16(w0lo + gb, &sm[db * 8192 + 4096 + (rowblk << 9)]);
    }
  };
  auto LOADA = [&](bf16x8 (&ah)[4], bf16x8 (&al)[4], int kt) {
    const int k0 = kt * 32;
    #pragma unroll
    for (int mt = 0; mt < 4; ++mt) {
      ah[mt] = *(const bf16x8*)&xhi[rowoff[mt] + k0];
      al[mt] = *(const bf16x8*)&xlo[rowoff[mt] + k0];
    }
  };
  auto COMPUTE = [&](const bf16x8 (&ah)[4], const bf16x8 (&al)[4], int db) {
    __builtin_amdgcn_s_setprio(1);
    #pragma unroll
    for (int nt = 0; nt < 4; ++nt) {
      int bb = db * 8192 + (wn + (nt << 4) + lr) * 32 + swrd;
      bf16x8 bh = *(const bf16x8*)&sm[bb];
      bf16x8 bl = *(const bf16x8*)&sm[bb + 4096];
      #pragma unroll
      for (int mt = 0; mt < 4; ++mt) {
        acc[mt][nt] = __builtin_amdgcn_mfma_f32_16x16x32_bf16(ah[mt], bh, acc[mt][nt], 0, 0, 0);
        acc[mt][nt] = __builtin_amdgcn_mfma_f32_16x16x32_bf16(al[mt], bh, acc[mt][nt], 0, 0, 0);
        acc[mt][nt] = __builtin_amdgcn_mfma_f32_16x16x32_bf16(ah[mt], bl, acc[mt][nt], 0, 0, 0);
      }
    }
    __builtin_amdgcn_s_setprio(0);
  };

  bf16x8 Ah0[4], Al0[4], Ah1[4], Al1[4];
  LOADA(Ah0, Al0, 0);
  STAGEB(0, 0);
  STAGEB(1, 1);
  for (int kt = 0; kt < 14; kt += 2) {
    SBAR();
    LOADA(Ah1, Al1, kt + 1);
    STAGEB(kt + 2, (kt + 2) % 3);
    VMCNT(16);
    SBAR();
    COMPUTE(Ah0, Al0, kt % 3);
    SBAR();
    LOADA(Ah0, Al0, kt + 2);
    STAGEB(kt + 3, (kt + 3) % 3);
    VMCNT(16);
    SBAR();
    COMPUTE(Ah1, Al1, (kt + 1) % 3);
  }
  SBAR();
  LOADA(Ah1, Al1, 15);
  VMCNT(12);
  SBAR();
  COMPUTE(Ah0, Al0, 2);
  SBAR();
  VMCNT(0);
  SBAR();
  COMPUTE(Ah1, Al1, 0);

  __syncthreads();
  float* smf = (float*)sm;
  float bi[4];
  #pragma unroll
  for (int nt = 0; nt < 4; ++nt) bi[nt] = b0[nbase + wn + (nt << 4) + lr];
  #pragma unroll
  for (int mt = 0; mt < 4; ++mt) {
    #pragma unroll
    for (int nt = 0; nt < 4; ++nt) {
      f32x4 v = acc[mt][nt];
      #pragma unroll
      for (int rr = 0; rr < 4; ++rr)
        smf[wv * 1088 + ((lg << 2) + rr) * 68 + (nt << 4) + lr] = v[rr] + bi[nt];
    }
    #pragma unroll
    for (int p = 0; p < 4; ++p) {
      int row = (p << 2) + (ln >> 4);
      int pos = tok0 + wm + (mt << 4) + row;
      if (pos < n0) {
        f32x4 vv = *(const f32x4*)&smf[wv * 1088 + row * 68 + ((ln & 15) << 2)];
        *(f32x4*)&h32[(size_t)perm[pos] * DHID + nbase + wn + ((ln & 15) << 2)] = vv;
      }
    }
  }
}

// ------------------------- fc1 E1 (shift expert, bf16x2) --------------------
__launch_bounds__(256, 2)
__global__ void k_fc1_e1(const unsigned short* __restrict__ xhi,
                         const unsigned short* __restrict__ xlo,
                         const unsigned short* __restrict__ w1q,
                         const float* __restrict__ b1,
                         const int* __restrict__ perm, const int* __restrict__ n0buf,
                         float* __restrict__ h32) {
  __shared__ unsigned short sm[12288];   // 24 KiB
  const int n0 = n0buf[0];
  const int t = threadIdx.x, wv = t >> 6, ln = t & 63;
  const int lr = ln & 15, lg = ln >> 4;
  const int g = blockIdx.x, q = g >> 3;
  const int tok0 = ((g & 7) + ((q >> 4) << 3)) * 128;
  const int nbase = (q & 15) * 128;
  if (tok0 + 128 <= n0) return;
  const int wm = (wv >> 1) * 64, wn = (wv & 1) * 64;

  int rowoff[4];
  #pragma unroll
  for (int mt = 0; mt < 4; ++mt)
    rowoff[mt] = perm[tok0 + wm + (mt << 4) + lr] * CIN + (lg << 3);

  const int swsrc = (((ln & 3) ^ ((ln >> 3) & 3)) << 3);
  const int swrd  = ((lg ^ ((lr >> 1) & 3)) << 3);

  f32x4 acc[4][4];
  #pragma unroll
  for (int i = 0; i < 4; ++i)
    #pragma unroll
    for (int j = 0; j < 4; ++j) acc[i][j] = f32x4{0.f, 0.f, 0.f, 0.f};

  auto STAGEB = [&](int kt, int db) {   // 2 GLDS per wave
    const int k0 = kt * 32;
    #pragma unroll
    for (int s = 0; s < 2; ++s) {
      const int rowblk = s * 4 + wv;
      size_t gb = (size_t)(nbase + (rowblk << 4) + (ln >> 2)) * CIN + k0 + swsrc;
      GLDS16(w1q + gb, &sm[db * 4096 + (rowblk << 9)]);
    }
  };
  auto LOADA = [&](bf16x8 (&ah)[4], bf16x8 (&al)[4], int kt) {
    const int k0 = kt * 32;
    #pragma unroll
    for (int mt = 0; mt < 4; ++mt) {
      ah[mt] = *(const bf16x8*)&xhi[rowoff[mt] + k0];
      al[mt] = *(const bf16x8*)&xlo[rowoff[mt] + k0];
    }
  };
  auto COMPUTE = [&](const bf16x8 (&ah)[4], const bf16x8 (&al)[4], int db) {
    __builtin_amdgcn_s_setprio(1);
    #pragma unroll
    for (int nt = 0; nt < 4; ++nt) {
      bf16x8 bq = *(const bf16x8*)&sm[db * 4096 + (wn + (nt << 4) + lr) * 32 + swrd];
      #pragma unroll
      for (int mt = 0; mt < 4; ++mt) {
        acc[mt][nt] = __builtin_amdgcn_mfma_f32_16x16x32_bf16(ah[mt], bq, acc[mt][nt], 0, 0, 0);
        acc[mt][nt] = __builtin_amdgcn_mfma_f32_16x16x32_bf16(al[mt], bq, acc[mt][nt], 0, 0, 0);
      }
    }
    __builtin_amdgcn_s_setprio(0);
  };

  bf16x8 Ah0[4], Al0[4], Ah1[4], Al1[4];
  LOADA(Ah0, Al0, 0);
  STAGEB(0, 0);
  STAGEB(1, 1);
  for (int kt = 0; kt < 14; kt += 2) {
    SBAR();
    LOADA(Ah1, Al1, kt + 1);
    STAGEB(kt + 2, (kt + 2) % 3);
    VMCNT(12);
    SBAR();
    COMPUTE(Ah0, Al0, kt % 3);
    SBAR();
    LOADA(Ah0, Al0, kt + 2);
    STAGEB(kt + 3, (kt + 3) % 3);
    VMCNT(12);
    SBAR();
    COMPUTE(Ah1, Al1, (kt + 1) % 3);
  }
  SBAR();
  LOADA(Ah1, Al1, 15);
  VMCNT(10);
  SBAR();
  COMPUTE(Ah0, Al0, 2);
  SBAR();
  VMCNT(0);
  SBAR();
  COMPUTE(Ah1, Al1, 0);

  __syncthreads();
  float* smf = (float*)sm;
  float bi[4];
  #pragma unroll
  for (int nt = 0; nt < 4; ++nt) bi[nt] = b1[nbase + wn + (nt << 4) + lr];
  #pragma unroll
  for (int mt = 0; mt < 4; ++mt) {
    #pragma unroll
    for (int nt = 0; nt < 4; ++nt) {
      f32x4 v = acc[mt][nt];
      #pragma unroll
      for (int rr = 0; rr < 4; ++rr)
        smf[wv * 1088 + ((lg << 2) + rr) * 68 + (nt << 4) + lr] = v[rr] + bi[nt];
    }
    #pragma unroll
    for (int p = 0; p < 4; ++p) {
      int row = (p << 2) + (ln >> 4);
      int pos = tok0 + wm + (mt << 4) + row;
      if (pos >= n0) {
        f32x4 vv = *(const f32x4*)&smf[wv * 1088 + row * 68 + ((ln & 15) << 2)];
        *(f32x4*)&h32[(size_t)perm[pos] * DHID + nbase + wn + ((ln & 15) << 2)] = vv;
      }
    }
  }
}

// ---------------- DWConv3x3 + bias + fast-exact GELU + gate2 partials -------
// R5 structure (high occupancy): block=(dc, ys, b), 40KB tile, simple loads.
// part transposed: part[(dc or 64+dc)*TOKS + tok] -> block-private rows.
__launch_bounds__(256)
__global__ void k_conv(const float* __restrict__ h32, const float* __restrict__ dww,
                       const float* __restrict__ dwb, const float* __restrict__ wg2,
                       unsigned short* __restrict__ hb, float* __restrict__ part) {
  __shared__ float4v tile[10][32][8];   // 40 KiB
  const int dc = blockIdx.x;   // 0..63 (32-d chunk)
  const int ys = blockIdx.y;   // 0..3
  const int b  = blockIdx.z;   // 0..15
  const int t = threadIdx.x;
  const int d0 = dc * 32, y0 = ys * 8;
  const int dl4 = t & 7, xq = t >> 3;

  #pragma unroll
  for (int ry = 0; ry < 10; ++ry) {
    int y = y0 - 1 + ry;
    float4v v = {0.f, 0.f, 0.f, 0.f};
    if (y >= 0 && y < 32)
      v = *(const float4v*)&h32[(size_t)(b * 1024 + y * 32 + xq) * DHID + d0 + dl4 * 4];
    tile[ry][xq][dl4] = v;
  }
  __syncthreads();

  const int d = d0 + dl4 * 4;
  float4v kk[9];
  #pragma unroll
  for (int i = 0; i < 9; ++i) {
    kk[i][0] = dww[(d + 0) * 9 + i]; kk[i][1] = dww[(d + 1) * 9 + i];
    kk[i][2] = dww[(d + 2) * 9 + i]; kk[i][3] = dww[(d + 3) * 9 + i];
  }
  const float4v bias = *(const float4v*)&dwb[d];
  float4v g0v, g1v;
  #pragma unroll
  for (int j = 0; j < 4; ++j) { g0v[j] = wg2[(d + j) * 2]; g1v[j] = wg2[(d + j) * 2 + 1]; }

  #pragma unroll
  for (int yy = 0; yy < 8; ++yy) {
    float4v s = bias;
    #pragma unroll
    for (int dy = 0; dy < 3; ++dy)
      #pragma unroll
      for (int dx = 0; dx < 3; ++dx) {
        int xs = xq + dx - 1;
        if (xs >= 0 && xs < 32) {
          float4v v = tile[yy + dy][xs][dl4];
          float4v k = kk[dy * 3 + dx];
          s[0] += v[0] * k[0]; s[1] += v[1] * k[1];
          s[2] += v[2] * k[2]; s[3] += v[3] * k[3];
        }
      }
    float4v gg;
    #pragma unroll
    for (int j = 0; j < 4; ++j) gg[j] = gelu_fast(s[j]);
    int tok = b * 1024 + (y0 + yy) * 32 + xq;
    ushort4v hv;
    #pragma unroll
    for (int j = 0; j < 4; ++j) hv[j] = f2bf(gg[j]);
    *(ushort4v*)&hb[(size_t)tok * DHID + d] = hv;
    float p0 = gg[0] * g0v[0] + gg[1] * g0v[1] + gg[2] * g0v[2] + gg[3] * g0v[3];
    float p1 = gg[0] * g1v[0] + gg[1] * g1v[1] + gg[2] * g1v[2] + gg[3] * g1v[3];
    p0 += __shfl_xor(p0, 1); p0 += __shfl_xor(p0, 2); p0 += __shfl_xor(p0, 4);
    p1 += __shfl_xor(p1, 1); p1 += __shfl_xor(p1, 2); p1 += __shfl_xor(p1, 4);
    if (dl4 == 0) {
      part[(size_t)dc * TOKS + tok] = p0;          // block-private row: coalesced
      part[(size_t)(64 + dc) * TOKS + tok] = p1;
    }
  }
}

// ------------------- gate 2 reduce (thread per token, coalesced) ------------
__global__ void k_gate2(const float* __restrict__ part, unsigned char* __restrict__ pick2) {
  int tok = blockIdx.x * 256 + threadIdx.x;
  float s0 = 0.f, s1 = 0.f;
  for (int i = 0; i < 64; ++i) {
    s0 += part[(size_t)i * TOKS + tok];
    s1 += part[(size_t)(64 + i) * TOKS + tok];
  }
  pick2[tok] = (s0 >= s1) ? 0 : 1;
}

// ------------------------- fc2 E0/E1: BK=64, A reg, B pipelined -------------
template <int EXPERT>
__launch_bounds__(256, 2)
__global__ void k_fc2_e(const unsigned short* __restrict__ hb,
                        const unsigned short* __restrict__ wb,
                        const float* __restrict__ bias_v,
                        const int* __restrict__ perm, const int* __restrict__ n0buf,
                        float* __restrict__ out) {
  __shared__ unsigned short sm[24576];   // 48 KiB
  const int n0 = n0buf[0];
  const int t = threadIdx.x, wv = t >> 6, ln = t & 63;
  const int lr = ln & 15, lg = ln >> 4;
  const int g = blockIdx.x, q = g >> 3;
  const int tok0 = ((g & 7) + ((q >> 2) << 3)) * 128;
  const int nbase = (q & 3) * 128;
  if (EXPERT == 0) { if (tok0 >= n0) return; }
  else             { if (tok0 + 128 <= n0) return; }
  const int wm = (wv >> 1) * 64, wn = (wv & 1) * 64;

  int rowoff[4];
  #pragma unroll
  for (int mt = 0; mt < 4; ++mt)
    rowoff[mt] = perm[tok0 + wm + (mt << 4) + lr] * DHID + (lg << 3);

  const int swsrc = (((ln & 3) ^ ((ln >> 3) & 3)) << 3);
  const int swrd  = ((lg ^ ((lr >> 1) & 3)) << 3);

  f32x4 acc[4][4];
  #pragma unroll
  for (int i = 0; i < 4; ++i)
    #pragma unroll
    for (int j = 0; j < 4; ++j) acc[i][j] = f32x4{0.f, 0.f, 0.f, 0.f};

  auto STAGEB = [&](int kt, int db) {   // 4 GLDS per wave
    #pragma unroll
    for (int ks = 0; ks < 2; ++ks) {
      const int k0 = kt * 64 + ks * 32;
      #pragma unroll
      for (int s = 0; s < 2; ++s) {
        const int rowblk = s * 4 + wv;
        size_t gb = (size_t)(nbase + (rowblk << 4) + (ln >> 2)) * DHID + k0 + swsrc;
        GLDS16(wb + gb, &sm[db * 8192 + ks * 4096 + (rowblk << 9)]);
      }
    }
  };
  auto LOADA = [&](bf16x8 (&a)[8], int kt) {
    #pragma unroll
    for (int ks = 0; ks < 2; ++ks) {
      const int k0 = kt * 64 + ks * 32;
      #pragma unroll
      for (int mt = 0; mt < 4; ++mt)
        a[ks * 4 + mt] = *(const bf16x8*)&hb[rowoff[mt] + k0];
    }
  };
  auto COMPUTE = [&](const bf16x8 (&a)[8], int db) {
    __builtin_amdgcn_s_setprio(1);
    #pragma unroll
    for (int ks = 0; ks < 2; ++ks) {
      #pragma unroll
      for (int nt = 0; nt < 4; ++nt) {
        bf16x8 bf = *(const bf16x8*)&sm[db * 8192 + ks * 4096 + (wn + (nt << 4) + lr) * 32 + swrd];
        #pragma unroll
        for (int mt = 0; mt < 4; ++mt)
          acc[mt][nt] = __builtin_amdgcn_mfma_f32_16x16x32_bf16(a[ks * 4 + mt], bf, acc[mt][nt], 0, 0, 0);
      }
    }
    __builtin_amdgcn_s_setprio(0);
  };

  bf16x8 A0[8], A1[8];
  LOADA(A0, 0);
  STAGEB(0, 0);
  STAGEB(1, 1);
  for (int kt = 0; kt < 30; kt += 2) {
    SBAR();
    LOADA(A1, kt + 1);
    STAGEB(kt + 2, (kt + 2) % 3);
    VMCNT(16);
    SBAR();
    COMPUTE(A0, kt % 3);
    SBAR();
    LOADA(A0, kt + 2);
    STAGEB(kt + 3, (kt + 3) % 3);
    VMCNT(16);
    SBAR();
    COMPUTE(A1, (kt + 1) % 3);
  }
  SBAR();
  LOADA(A1, 31);
  VMCNT(12);
  SBAR();
  COMPUTE(A0, 0);
  SBAR();
  VMCNT(0);
  SBAR();
  COMPUTE(A1, 1);

  __syncthreads();
  float* smf = (float*)sm;
  float bi[4];
  #pragma unroll
  for (int nt = 0; nt < 4; ++nt) bi[nt] = bias_v[nbase + wn + (nt << 4) + lr];
  #pragma unroll
  for (int mt = 0; mt < 4; ++mt) {
    #pragma unroll
    for (int nt = 0; nt < 4; ++nt) {
      f32x4 v = acc[mt][nt];
      #pragma unroll
      for (int rr = 0; rr < 4; ++rr)
        smf[wv * 1088 + ((lg << 2) + rr) * 68 + (nt << 4) + lr] = v[rr] + bi[nt];
    }
    #pragma unroll
    for (int p = 0; p < 4; ++p) {
      int row = (p << 2) + (ln >> 4);
      int pos = tok0 + wm + (mt << 4) + row;
      bool store = (EXPERT == 0) ? (pos < n0) : (pos >= n0);
      if (store) {
        f32x4 vv = *(const f32x4*)&smf[wv * 1088 + row * 68 + ((ln & 15) << 2)];
        *(f32x4*)&out[(size_t)perm[pos] * CIN + nbase + wn + ((ln & 15) << 2)] = vv;
      }
    }
  }
}

// ---------------------------------------------------------------------------
extern "C" void kernel_launch(void* const* d_in, const int* in_sizes, int n_in,
                              void* d_out, int out_size, void* d_ws, size_t ws_size,
                              hipStream_t stream) {
  (void)in_sizes; (void)n_in; (void)out_size; (void)ws_size;
  const float* x   = (const float*)d_in[0];
  const float* wg1 = (const float*)d_in[3];
  const float* w0  = (const float*)d_in[4];
  const float* b0  = (const float*)d_in[5];
  const float* w1  = (const float*)d_in[6];
  const float* b1  = (const float*)d_in[7];
  const float* dww = (const float*)d_in[8];
  const float* dwb = (const float*)d_in[9];
  const float* wg2 = (const float*)d_in[10];
  const float* w20 = (const float*)d_in[11];
  const float* b20 = (const float*)d_in[12];
  const float* w21 = (const float*)d_in[13];
  const float* b21 = (const float*)d_in[14];
  float* out = (float*)d_out;

  char* ws = (char*)d_ws;
  const size_t MB2 = 1u << 21;
  unsigned short* w0hi = (unsigned short*)(ws + 0 * MB2);
  unsigned short* w0lo = (unsigned short*)(ws + 1 * MB2);
  unsigned short* w1q  = (unsigned short*)(ws + 2 * MB2);
  unsigned short* w20b = (unsigned short*)(ws + 3 * MB2);
  unsigned short* w21b = (unsigned short*)(ws + 4 * MB2);
  char* p = ws + 5 * MB2;
  unsigned short* xhi = (unsigned short*)p;            p += (size_t)TOKS * CIN * 2;
  unsigned short* xlo = (unsigned short*)p;            p += (size_t)TOKS * CIN * 2;
  unsigned char* pick1 = (unsigned char*)p;            p += 65536;
  unsigned char* pick2 = (unsigned char*)p;            p += 65536;
  int* perm1 = (int*)p;                                p += TOKS * 4;
  int* perm2 = (int*)p;                                p += TOKS * 4;
  int* n0a   = (int*)p;                                p += 256;
  int* n0b   = (int*)p;                                p += 256;
  float* part = (float*)p;                             p += (size_t)TOKS * 128 * 4;
  float* h32  = (float*)p;                             p += (size_t)TOKS * DHID * 4;
  unsigned short* hb = (unsigned short*)p;             // +64 MiB; total ~245 MiB

  k_prep <<<8192, 256, 0, stream>>>(w0, w1, w20, w21, w0hi, w0lo, w1q, w20b, w21b,
                                    x, wg1, xhi, xlo, pick1);
  k_scan <<<1, 1024, 0, stream>>>(pick1, perm1, n0a);
  k_fc1_e0<<<2048, 256, 0, stream>>>(xhi, xlo, w0hi, w0lo, b0, perm1, n0a, h32);
  k_fc1_e1<<<2048, 256, 0, stream>>>(xhi, xlo, w1q, b1, perm1, n0a, h32);
  k_conv <<<dim3(64, 4, 16), 256, 0, stream>>>(h32, dww, dwb, wg2, hb, part);
  k_gate2<<<64, 256, 0, stream>>>(part, pick2);
  k_scan <<<1, 1024, 0, stream>>>(pick2, perm2, n0b);
  k_fc2_e<0><<<512, 256, 0, stream>>>(hb, w20b, b20, perm2, n0b, out);
  k_fc2_e<1><<<512, 256, 0, stream>>>(hb, w21b, b21, perm2, n0b, out);
}

// Round 9
// 378.739 us; speedup vs baseline: 1.8243x; 1.0609x over previous
//
#include <hip/hip_runtime.h>
#include <hip/hip_bf16.h>

// ---------------------------------------------------------------------------
// Mlp_FMoE: fc1(MoE 2-expert top-1) -> DWConv3x3 -> GELU(exact) -> fc2(MoE)
// B=16 N=1024 C=512 Dh=2048 H=W=32, fp32 in/out.
// R9: merged per-expert GEMM kernels (one launch each): block-uniform expert
//     classification; pure blocks run their expert's proven pipeline; the few
//     mixed blocks run both passes sequentially with one acc set. Doubles
//     active blocks/CU (R8: half the grid exited -> occupancy 16%).
// ---------------------------------------------------------------------------

#define TOKS  16384
#define CIN   512
#define DHID  2048

typedef __attribute__((ext_vector_type(8))) __bf16 bf16x8;
typedef __attribute__((ext_vector_type(4))) float  f32x4;
typedef __attribute__((ext_vector_type(4))) float  float4v;
typedef __attribute__((ext_vector_type(4))) unsigned short ushort4v;
typedef __attribute__((ext_vector_type(8))) unsigned short ushort8;

__device__ __forceinline__ unsigned short f2bf(float f) {
  union { float f; unsigned int u; } a; a.f = f;
  unsigned int u = a.u;
  unsigned int r = u + 0x7FFFu + ((u >> 16) & 1u);   // RNE
  return (unsigned short)(r >> 16);
}
__device__ __forceinline__ float bf2f(unsigned short h) {
  union { unsigned int u; float f; } a; a.u = ((unsigned int)h) << 16;
  return a.f;
}

// shift_quant: sign(w)*2^clip(round(log2(|w|+1e-12)),-14,0).
// round(log2(aw)) == e + (mantissa > sqrt(2)); exact via mantissa bit test.
__device__ __forceinline__ float squant(float w) {
  if (w == 0.0f) return 0.0f;
  float aw = fabsf(w) + 1e-12f;                 // fp32 add, as reference
  union { float f; unsigned u; } a; a.f = aw;
  int e = (int)((a.u >> 23) & 0xFFu) - 127;
  unsigned frac = a.u & 0x7FFFFFu;
  int shift = e + (frac >= 0x3504F4u ? 1 : 0);  // frac of sqrt(2)
  shift = min(max(shift, -14), 0);
  union { unsigned u; float f; } q; q.u = (unsigned)(shift + 127) << 23;
  return (w > 0.0f) ? q.f : -q.f;
}

// gelu via Abramowitz-Stegun 7.1.26 erf (|eps| <= 1.5e-7)
__device__ __forceinline__ float gelu_fast(float s) {
  float z = fabsf(s) * 0.70710678118654752f;
  float zz = z * z;
#if __has_builtin(__builtin_amdgcn_exp2f)
  float e = __builtin_amdgcn_exp2f(zz * -1.4426950408889634f);
#else
  float e = exp2f(zz * -1.4426950408889634f);
#endif
  float d = fmaf(0.3275911f, z, 1.0f);
#if __has_builtin(__builtin_amdgcn_rcpf)
  float t = __builtin_amdgcn_rcpf(d);
#else
  float t = 1.0f / d;
#endif
  float p = fmaf(1.061405429f, t, -1.453152027f);
  p = fmaf(p, t, 1.421413741f);
  p = fmaf(p, t, -0.284496736f);
  p = fmaf(p, t, 0.254829592f);
  p = p * t;
  float erfz = fmaf(-p, e, 1.0f);
  float er = (s < 0.0f) ? -erfz : erfz;
  return 0.5f * s * (1.0f + er);
}

#define GLDS16(gp, lp) __builtin_amdgcn_global_load_lds(                      \
    (const __attribute__((address_space(1))) void*)(gp),                      \
    (__attribute__((address_space(3))) void*)(lp), 16, 0, 0)

#define SBAR()  { __builtin_amdgcn_s_barrier(); __builtin_amdgcn_sched_barrier(0); }
#define VMCNT(n) asm volatile("s_waitcnt vmcnt(" #n ")" ::: "memory")

// ------------- merged prep: weights (blocks<4096) + x split/gate1 -----------
__global__ void k_prep(const float* __restrict__ w0, const float* __restrict__ w1,
                       const float* __restrict__ w20, const float* __restrict__ w21,
                       unsigned short* __restrict__ w0hi, unsigned short* __restrict__ w0lo,
                       unsigned short* __restrict__ w1q, unsigned short* __restrict__ w20b,
                       unsigned short* __restrict__ w21b,
                       const float* __restrict__ x, const float* __restrict__ wg1,
                       unsigned short* __restrict__ xhi, unsigned short* __restrict__ xlo,
                       unsigned char* __restrict__ pick1) {
  __shared__ float wg[1024];
  const int t = threadIdx.x;
  if (blockIdx.x < 4096) {
    int i = blockIdx.x * 256 + t;
    float v = w0[i];
    unsigned short h = f2bf(v);
    w0hi[i] = h;
    w0lo[i] = f2bf(v - bf2f(h));
    w1q[i]  = f2bf(squant(w1[i]));
    w20b[i] = f2bf(w20[i]);
    w21b[i] = f2bf(squant(w21[i]));
    return;
  }
  const int bid = blockIdx.x - 4096;
  #pragma unroll
  for (int i = 0; i < 4; ++i) wg[t + i * 256] = wg1[t + i * 256];
  __syncthreads();
  const int tok = bid * 4 + (t >> 6);
  const int l = t & 63;
  const float* xr = x + (size_t)tok * CIN + l * 8;
  float4v v0 = *(const float4v*)xr;
  float4v v1 = *(const float4v*)(xr + 4);
  float s0 = 0.f, s1 = 0.f;
  ushort8 hv, lv;
  #pragma unroll
  for (int j = 0; j < 8; ++j) {
    float v = (j < 4) ? v0[j] : v1[j - 4];
    unsigned short h = f2bf(v);
    hv[j] = h;
    lv[j] = f2bf(v - bf2f(h));
    int c = l * 8 + j;
    s0 += v * wg[c * 2];
    s1 += v * wg[c * 2 + 1];
  }
  *(ushort8*)&xhi[(size_t)tok * CIN + l * 8] = hv;
  *(ushort8*)&xlo[(size_t)tok * CIN + l * 8] = lv;
  for (int m = 32; m; m >>= 1) { s0 += __shfl_xor(s0, m); s1 += __shfl_xor(s1, m); }
  if (l == 0) pick1[tok] = (s0 >= s1) ? 0 : 1;   // argmax==0 on tie
}

// --------------- stable partition: perm = [expert0 toks..., expert1 toks...]
__global__ void k_scan(const unsigned char* __restrict__ pick, int* __restrict__ perm,
                       int* __restrict__ n0buf) {
  __shared__ int wpre[17];
  const int t = threadIdx.x;            // 1024
  const int lane = t & 63, w = t >> 6;  // 16 waves
  unsigned char loc[16]; int c0 = 0;
  #pragma unroll
  for (int i = 0; i < 16; ++i) { loc[i] = pick[t * 16 + i]; c0 += (loc[i] == 0); }
  int s = c0;
  #pragma unroll
  for (int off = 1; off < 64; off <<= 1) {
    int v = __shfl_up(s, off);
    if (lane >= off) s += v;
  }
  if (lane == 63) wpre[w + 1] = s;
  if (t == 0) wpre[0] = 0;
  __syncthreads();
  if (t == 0) {
    for (int j = 1; j <= 16; ++j) wpre[j] += wpre[j - 1];
    n0buf[0] = wpre[16];
  }
  __syncthreads();
  int total0 = wpre[16];
  int pre0 = wpre[w] + s - c0;
  int pre1 = t * 16 - pre0;
  int p0 = pre0, p1 = total0 + pre1;
  #pragma unroll
  for (int i = 0; i < 16; ++i) {
    int tok = t * 16 + i;
    if (loc[i] == 0) perm[p0++] = tok; else perm[p1++] = tok;
  }
}

// ------------------- fc1 merged: per-block expert dispatch ------------------
// 128x128 tile, BK=32. Pure-E0 blocks: 3-chain pipeline over {w0hi,w0lo}.
// Pure-E1: 2-chain over {w1q}. Mixed (<=16 blocks): both passes, one acc set.
__launch_bounds__(256, 2)
__global__ void k_fc1(const unsigned short* __restrict__ xhi,
                      const unsigned short* __restrict__ xlo,
                      const unsigned short* __restrict__ w0hi,
                      const unsigned short* __restrict__ w0lo,
                      const unsigned short* __restrict__ w1q,
                      const float* __restrict__ b0, const float* __restrict__ b1,
                      const int* __restrict__ perm, const int* __restrict__ n0buf,
                      float* __restrict__ h32) {
  __shared__ unsigned short sm[24576];   // 48 KiB (E0 path max: 3 bufs x 2 planes)
  const int n0 = n0buf[0];
  const int t = threadIdx.x, wv = t >> 6, ln = t & 63;
  const int lr = ln & 15, lg = ln >> 4;
  const int g = blockIdx.x, q = g >> 3;
  const int tok0 = ((g & 7) + ((q >> 4) << 3)) * 128;
  const int nbase = (q & 15) * 128;
  const int wm = (wv >> 1) * 64, wn = (wv & 1) * 64;
  const bool hasE0 = (tok0 < n0), hasE1 = (tok0 + 128 > n0);

  int rowoff[4];
  #pragma unroll
  for (int mt = 0; mt < 4; ++mt)
    rowoff[mt] = perm[tok0 + wm + (mt << 4) + lr] * CIN + (lg << 3);

  const int swsrc = (((ln & 3) ^ ((ln >> 3) & 3)) << 3);
  const int swrd  = ((lg ^ ((lr >> 1) & 3)) << 3);

  f32x4 acc[4][4];

  auto ZERO = [&]() {
    #pragma unroll
    for (int i = 0; i < 4; ++i)
      #pragma unroll
      for (int j = 0; j < 4; ++j) acc[i][j] = f32x4{0.f, 0.f, 0.f, 0.f};
  };
  auto LOADA = [&](bf16x8 (&ah)[4], bf16x8 (&al)[4], int kt) {
    const int k0 = kt * 32;
    #pragma unroll
    for (int mt = 0; mt < 4; ++mt) {
      ah[mt] = *(const bf16x8*)&xhi[rowoff[mt] + k0];
      al[mt] = *(const bf16x8*)&xlo[rowoff[mt] + k0];
    }
  };

  auto RUN_E0 = [&]() {
    auto STAGEB = [&](int kt, int db) {   // 4 GLDS per wave
      const int k0 = kt * 32;
      #pragma unroll
      for (int s = 0; s < 2; ++s) {
        const int rowblk = s * 4 + wv;
        size_t gb = (size_t)(nbase + (rowblk << 4) + (ln >> 2)) * CIN + k0 + swsrc;
        GLDS16(w0hi + gb, &sm[db * 8192 + (rowblk << 9)]);
        GLDS16(w0lo + gb, &sm[db * 8192 + 4096 + (rowblk << 9)]);
      }
    };
    auto COMPUTE = [&](const bf16x8 (&ah)[4], const bf16x8 (&al)[4], int db) {
      __builtin_amdgcn_s_setprio(1);
      #pragma unroll
      for (int nt = 0; nt < 4; ++nt) {
        int bb = db * 8192 + (wn + (nt << 4) + lr) * 32 + swrd;
        bf16x8 bh = *(const bf16x8*)&sm[bb];
        bf16x8 bl = *(const bf16x8*)&sm[bb + 4096];
        #pragma unroll
        for (int mt = 0; mt < 4; ++mt) {
          acc[mt][nt] = __builtin_amdgcn_mfma_f32_16x16x32_bf16(ah[mt], bh, acc[mt][nt], 0, 0, 0);
          acc[mt][nt] = __builtin_amdgcn_mfma_f32_16x16x32_bf16(al[mt], bh, acc[mt][nt], 0, 0, 0);
          acc[mt][nt] = __builtin_amdgcn_mfma_f32_16x16x32_bf16(ah[mt], bl, acc[mt][nt], 0, 0, 0);
        }
      }
      __builtin_amdgcn_s_setprio(0);
    };
    bf16x8 Ah0[4], Al0[4], Ah1[4], Al1[4];
    LOADA(Ah0, Al0, 0);
    STAGEB(0, 0);
    STAGEB(1, 1);
    for (int kt = 0; kt < 14; kt += 2) {
      SBAR();
      LOADA(Ah1, Al1, kt + 1);
      STAGEB(kt + 2, (kt + 2) % 3);
      VMCNT(16);
      SBAR();
      COMPUTE(Ah0, Al0, kt % 3);
      SBAR();
      LOADA(Ah0, Al0, kt + 2);
      STAGEB(kt + 3, (kt + 3) % 3);
      VMCNT(16);
      SBAR();
      COMPUTE(Ah1, Al1, (kt + 1) % 3);
    }
    SBAR();
    LOADA(Ah1, Al1, 15);
    VMCNT(12);
    SBAR();
    COMPUTE(Ah0, Al0, 2);
    SBAR();
    VMCNT(0);
    SBAR();
    COMPUTE(Ah1, Al1, 0);
  };

  auto RUN_E1 = [&]() {
    auto STAGEB = [&](int kt, int db) {   // 2 GLDS per wave
      const int k0 = kt * 32;
      #pragma unroll
      for (int s = 0; s < 2; ++s) {
        const int rowblk = s * 4 + wv;
        size_t gb = (size_t)(nbase + (rowblk << 4) + (ln >> 2)) * CIN + k0 + swsrc;
        GLDS16(w1q + gb, &sm[db * 4096 + (rowblk << 9)]);
      }
    };
    auto COMPUTE = [&](const bf16x8 (&ah)[4], const bf16x8 (&al)[4], int db) {
      __builtin_amdgcn_s_setprio(1);
      #pragma unroll
      for (int nt = 0; nt < 4; ++nt) {
        bf16x8 bq = *(const bf16x8*)&sm[db * 4096 + (wn + (nt << 4) + lr) * 32 + swrd];
        #pragma unroll
        for (int mt = 0; mt < 4; ++mt) {
          acc[mt][nt] = __builtin_amdgcn_mfma_f32_16x16x32_bf16(ah[mt], bq, acc[mt][nt], 0, 0, 0);
          acc[mt][nt] = __builtin_amdgcn_mfma_f32_16x16x32_bf16(al[mt], bq, acc[mt][nt], 0, 0, 0);
        }
      }
      __builtin_amdgcn_s_setprio(0);
    };
    bf16x8 Ah0[4], Al0[4], Ah1[4], Al1[4];
    LOADA(Ah0, Al0, 0);
    STAGEB(0, 0);
    STAGEB(1, 1);
    for (int kt = 0; kt < 14; kt += 2) {
      SBAR();
      LOADA(Ah1, Al1, kt + 1);
      STAGEB(kt + 2, (kt + 2) % 3);
      VMCNT(12);
      SBAR();
      COMPUTE(Ah0, Al0, kt % 3);
      SBAR();
      LOADA(Ah0, Al0, kt + 2);
      STAGEB(kt + 3, (kt + 3) % 3);
      VMCNT(12);
      SBAR();
      COMPUTE(Ah1, Al1, (kt + 1) % 3);
    }
    SBAR();
    LOADA(Ah1, Al1, 15);
    VMCNT(10);
    SBAR();
    COMPUTE(Ah0, Al0, 2);
    SBAR();
    VMCNT(0);
    SBAR();
    COMPUTE(Ah1, Al1, 0);
  };

  auto EPI = [&](const float* bias_v, bool isE0) {
    __syncthreads();
    float* smf = (float*)sm;
    float bi[4];
    #pragma unroll
    for (int nt = 0; nt < 4; ++nt) bi[nt] = bias_v[nbase + wn + (nt << 4) + lr];
    #pragma unroll
    for (int mt = 0; mt < 4; ++mt) {
      #pragma unroll
      for (int nt = 0; nt < 4; ++nt) {
        f32x4 v = acc[mt][nt];
        #pragma unroll
        for (int rr = 0; rr < 4; ++rr)
          smf[wv * 1088 + ((lg << 2) + rr) * 68 + (nt << 4) + lr] = v[rr] + bi[nt];
      }
      #pragma unroll
      for (int p = 0; p < 4; ++p) {
        int row = (p << 2) + (ln >> 4);
        int pos = tok0 + wm + (mt << 4) + row;
        bool sel = isE0 ? (pos < n0) : (pos >= n0);
        if (sel) {
          f32x4 vv = *(const f32x4*)&smf[wv * 1088 + row * 68 + ((ln & 15) << 2)];
          *(f32x4*)&h32[(size_t)perm[pos] * DHID + nbase + wn + ((ln & 15) << 2)] = vv;
        }
      }
    }
  };

  if (hasE0) { ZERO(); RUN_E0(); EPI(b0, true); }
  if (hasE1) {
    __syncthreads();   // sm reuse: wait for EPI readers (mixed) / uniform no-op
    ZERO(); RUN_E1(); EPI(b1, false);
  }
}

// ---------------- DWConv3x3 + bias + fast-exact GELU + gate2 partials -------
__launch_bounds__(256)
__global__ void k_conv(const float* __restrict__ h32, const float* __restrict__ dww,
                       const float* __restrict__ dwb, const float* __restrict__ wg2,
                       unsigned short* __restrict__ hb, float* __restrict__ part) {
  __shared__ float4v tile[10][32][8];   // 40 KiB
  const int dc = blockIdx.x;   // 0..63 (32-d chunk)
  const int ys = blockIdx.y;   // 0..3
  const int b  = blockIdx.z;   // 0..15
  const int t = threadIdx.x;
  const int d0 = dc * 32, y0 = ys * 8;
  const int dl4 = t & 7, xq = t >> 3;

  #pragma unroll
  for (int ry = 0; ry < 10; ++ry) {
    int y = y0 - 1 + ry;
    float4v v = {0.f, 0.f, 0.f, 0.f};
    if (y >= 0 && y < 32)
      v = *(const float4v*)&h32[(size_t)(b * 1024 + y * 32 + xq) * DHID + d0 + dl4 * 4];
    tile[ry][xq][dl4] = v;
  }
  __syncthreads();

  const int d = d0 + dl4 * 4;
  float4v kk[9];
  #pragma unroll
  for (int i = 0; i < 9; ++i) {
    kk[i][0] = dww[(d + 0) * 9 + i]; kk[i][1] = dww[(d + 1) * 9 + i];
    kk[i][2] = dww[(d + 2) * 9 + i]; kk[i][3] = dww[(d + 3) * 9 + i];
  }
  const float4v bias = *(const float4v*)&dwb[d];
  float4v g0v, g1v;
  #pragma unroll
  for (int j = 0; j < 4; ++j) { g0v[j] = wg2[(d + j) * 2]; g1v[j] = wg2[(d + j) * 2 + 1]; }

  #pragma unroll
  for (int yy = 0; yy < 8; ++yy) {
    float4v s = bias;
    #pragma unroll
    for (int dy = 0; dy < 3; ++dy)
      #pragma unroll
      for (int dx = 0; dx < 3; ++dx) {
        int xs = xq + dx - 1;
        if (xs >= 0 && xs < 32) {
          float4v v = tile[yy + dy][xs][dl4];
          float4v k = kk[dy * 3 + dx];
          s[0] += v[0] * k[0]; s[1] += v[1] * k[1];
          s[2] += v[2] * k[2]; s[3] += v[3] * k[3];
        }
      }
    float4v gg;
    #pragma unroll
    for (int j = 0; j < 4; ++j) gg[j] = gelu_fast(s[j]);
    int tok = b * 1024 + (y0 + yy) * 32 + xq;
    ushort4v hv;
    #pragma unroll
    for (int j = 0; j < 4; ++j) hv[j] = f2bf(gg[j]);
    *(ushort4v*)&hb[(size_t)tok * DHID + d] = hv;
    float p0 = gg[0] * g0v[0] + gg[1] * g0v[1] + gg[2] * g0v[2] + gg[3] * g0v[3];
    float p1 = gg[0] * g1v[0] + gg[1] * g1v[1] + gg[2] * g1v[2] + gg[3] * g1v[3];
    p0 += __shfl_xor(p0, 1); p0 += __shfl_xor(p0, 2); p0 += __shfl_xor(p0, 4);
    p1 += __shfl_xor(p1, 1); p1 += __shfl_xor(p1, 2); p1 += __shfl_xor(p1, 4);
    if (dl4 == 0) {
      part[(size_t)dc * TOKS + tok] = p0;          // block-private row: coalesced
      part[(size_t)(64 + dc) * TOKS + tok] = p1;
    }
  }
}

// ------------------- gate 2 reduce (thread per token, coalesced) ------------
__global__ void k_gate2(const float* __restrict__ part, unsigned char* __restrict__ pick2) {
  int tok = blockIdx.x * 256 + threadIdx.x;
  float s0 = 0.f, s1 = 0.f;
  for (int i = 0; i < 64; ++i) {
    s0 += part[(size_t)i * TOKS + tok];
    s1 += part[(size_t)(64 + i) * TOKS + tok];
  }
  pick2[tok] = (s0 >= s1) ? 0 : 1;
}

// ------------------- fc2 merged: per-block expert dispatch ------------------
// 128x128, BK=64; pure blocks run the proven single-plane pipeline with their
// expert's weights; mixed blocks run both passes with one acc set.
__launch_bounds__(256, 2)
__global__ void k_fc2(const unsigned short* __restrict__ hb,
                      const unsigned short* __restrict__ w20b,
                      const unsigned short* __restrict__ w21b,
                      const float* __restrict__ b20, const float* __restrict__ b21,
                      const int* __restrict__ perm, const int* __restrict__ n0buf,
                      float* __restrict__ out) {
  __shared__ unsigned short sm[24576];   // 48 KiB (3 bufs x 2 ksub x 4096)
  const int n0 = n0buf[0];
  const int t = threadIdx.x, wv = t >> 6, ln = t & 63;
  const int lr = ln & 15, lg = ln >> 4;
  const int g = blockIdx.x, q = g >> 3;
  const int tok0 = ((g & 7) + ((q >> 2) << 3)) * 128;
  const int nbase = (q & 3) * 128;
  const int wm = (wv >> 1) * 64, wn = (wv & 1) * 64;
  const bool hasE0 = (tok0 < n0), hasE1 = (tok0 + 128 > n0);

  int rowoff[4];
  #pragma unroll
  for (int mt = 0; mt < 4; ++mt)
    rowoff[mt] = perm[tok0 + wm + (mt << 4) + lr] * DHID + (lg << 3);

  const int swsrc = (((ln & 3) ^ ((ln >> 3) & 3)) << 3);
  const int swrd  = ((lg ^ ((lr >> 1) & 3)) << 3);

  f32x4 acc[4][4];
  auto ZERO = [&]() {
    #pragma unroll
    for (int i = 0; i < 4; ++i)
      #pragma unroll
      for (int j = 0; j < 4; ++j) acc[i][j] = f32x4{0.f, 0.f, 0.f, 0.f};
  };
  auto LOADA = [&](bf16x8 (&a)[8], int kt) {
    #pragma unroll
    for (int ks = 0; ks < 2; ++ks) {
      const int k0 = kt * 64 + ks * 32;
      #pragma unroll
      for (int mt = 0; mt < 4; ++mt)
        a[ks * 4 + mt] = *(const bf16x8*)&hb[rowoff[mt] + k0];
    }
  };

  auto RUN = [&](const unsigned short* __restrict__ wb) {
    auto STAGEB = [&](int kt, int db) {   // 4 GLDS per wave
      #pragma unroll
      for (int ks = 0; ks < 2; ++ks) {
        const int k0 = kt * 64 + ks * 32;
        #pragma unroll
        for (int s = 0; s < 2; ++s) {
          const int rowblk = s * 4 + wv;
          size_t gb = (size_t)(nbase + (rowblk << 4) + (ln >> 2)) * DHID + k0 + swsrc;
          GLDS16(wb + gb, &sm[db * 8192 + ks * 4096 + (rowblk << 9)]);
        }
      }
    };
    auto COMPUTE = [&](const bf16x8 (&a)[8], int db) {
      __builtin_amdgcn_s_setprio(1);
      #pragma unroll
      for (int ks = 0; ks < 2; ++ks) {
        #pragma unroll
        for (int nt = 0; nt < 4; ++nt) {
          bf16x8 bf = *(const bf16x8*)&sm[db * 8192 + ks * 4096 + (wn + (nt << 4) + lr) * 32 + swrd];
          #pragma unroll
          for (int mt = 0; mt < 4; ++mt)
            acc[mt][nt] = __builtin_amdgcn_mfma_f32_16x16x32_bf16(a[ks * 4 + mt], bf, acc[mt][nt], 0, 0, 0);
        }
      }
      __builtin_amdgcn_s_setprio(0);
    };
    bf16x8 A0[8], A1[8];
    LOADA(A0, 0);
    STAGEB(0, 0);
    STAGEB(1, 1);
    for (int kt = 0; kt < 30; kt += 2) {
      SBAR();
      LOADA(A1, kt + 1);
      STAGEB(kt + 2, (kt + 2) % 3);
      VMCNT(16);
      SBAR();
      COMPUTE(A0, kt % 3);
      SBAR();
      LOADA(A0, kt + 2);
      STAGEB(kt + 3, (kt + 3) % 3);
      VMCNT(16);
      SBAR();
      COMPUTE(A1, (kt + 1) % 3);
    }
    SBAR();
    LOADA(A1, 31);
    VMCNT(12);
    SBAR();
    COMPUTE(A0, 0);
    SBAR();
    VMCNT(0);
    SBAR();
    COMPUTE(A1, 1);
  };

  auto EPI = [&](const float* bias_v, bool isE0) {
    __syncthreads();
    float* smf = (float*)sm;
    float bi[4];
    #pragma unroll
    for (int nt = 0; nt < 4; ++nt) bi[nt] = bias_v[nbase + wn + (nt << 4) + lr];
    #pragma unroll
    for (int mt = 0; mt < 4; ++mt) {
      #pragma unroll
      for (int nt = 0; nt < 4; ++nt) {
        f32x4 v = acc[mt][nt];
        #pragma unroll
        for (int rr = 0; rr < 4; ++rr)
          smf[wv * 1088 + ((lg << 2) + rr) * 68 + (nt << 4) + lr] = v[rr] + bi[nt];
      }
      #pragma unroll
      for (int p = 0; p < 4; ++p) {
        int row = (p << 2) + (ln >> 4);
        int pos = tok0 + wm + (mt << 4) + row;
        bool sel = isE0 ? (pos < n0) : (pos >= n0);
        if (sel) {
          f32x4 vv = *(const f32x4*)&smf[wv * 1088 + row * 68 + ((ln & 15) << 2)];
          *(f32x4*)&out[(size_t)perm[pos] * CIN + nbase + wn + ((ln & 15) << 2)] = vv;
        }
      }
    }
  };

  if (hasE0) { ZERO(); RUN(w20b); EPI(b20, true); }
  if (hasE1) {
    __syncthreads();
    ZERO(); RUN(w21b); EPI(b21, false);
  }
}

// ---------------------------------------------------------------------------
extern "C" void kernel_launch(void* const* d_in, const int* in_sizes, int n_in,
                              void* d_out, int out_size, void* d_ws, size_t ws_size,
                              hipStream_t stream) {
  (void)in_sizes; (void)n_in; (void)out_size; (void)ws_size;
  const float* x   = (const float*)d_in[0];
  const float* wg1 = (const float*)d_in[3];
  const float* w0  = (const float*)d_in[4];
  const float* b0  = (const float*)d_in[5];
  const float* w1  = (const float*)d_in[6];
  const float* b1  = (const float*)d_in[7];
  const float* dww = (const float*)d_in[8];
  const float* dwb = (const float*)d_in[9];
  const float* wg2 = (const float*)d_in[10];
  const float* w20 = (const float*)d_in[11];
  const float* b20 = (const float*)d_in[12];
  const float* w21 = (const float*)d_in[13];
  const float* b21 = (const float*)d_in[14];
  float* out = (float*)d_out;

  char* ws = (char*)d_ws;
  const size_t MB2 = 1u << 21;
  unsigned short* w0hi = (unsigned short*)(ws + 0 * MB2);
  unsigned short* w0lo = (unsigned short*)(ws + 1 * MB2);
  unsigned short* w1q  = (unsigned short*)(ws + 2 * MB2);
  unsigned short* w20b = (unsigned short*)(ws + 3 * MB2);
  unsigned short* w21b = (unsigned short*)(ws + 4 * MB2);
  char* p = ws + 5 * MB2;
  unsigned short* xhi = (unsigned short*)p;            p += (size_t)TOKS * CIN * 2;
  unsigned short* xlo = (unsigned short*)p;            p += (size_t)TOKS * CIN * 2;
  unsigned char* pick1 = (unsigned char*)p;            p += 65536;
  unsigned char* pick2 = (unsigned char*)p;            p += 65536;
  int* perm1 = (int*)p;                                p += TOKS * 4;
  int* perm2 = (int*)p;                                p += TOKS * 4;
  int* n0a   = (int*)p;                                p += 256;
  int* n0b   = (int*)p;                                p += 256;
  float* part = (float*)p;                             p += (size_t)TOKS * 128 * 4;
  float* h32  = (float*)p;                             p += (size_t)TOKS * DHID * 4;
  unsigned short* hb = (unsigned short*)p;             // +64 MiB; total ~245 MiB

  k_prep <<<8192, 256, 0, stream>>>(w0, w1, w20, w21, w0hi, w0lo, w1q, w20b, w21b,
                                    x, wg1, xhi, xlo, pick1);
  k_scan <<<1, 1024, 0, stream>>>(pick1, perm1, n0a);
  k_fc1  <<<2048, 256, 0, stream>>>(xhi, xlo, w0hi, w0lo, w1q, b0, b1, perm1, n0a, h32);
  k_conv <<<dim3(64, 4, 16), 256, 0, stream>>>(h32, dww, dwb, wg2, hb, part);
  k_gate2<<<64, 256, 0, stream>>>(part, pick2);
  k_scan <<<1, 1024, 0, stream>>>(pick2, perm2, n0b);
  k_fc2  <<<512, 256, 0, stream>>>(hb, w20b, w21b, b20, b21, perm2, n0b, out);
}